// Round 5
// baseline (194.759 us; speedup 1.0000x reference)
//
#include <hip/hip_runtime.h>
#include <hip/hip_bf16.h>
#include <math.h>

#define M_TOK 16
#define NDIM  2048
#define DHEAD 128
#define NHEAD 16
#define MAXLEN 8448
#define FFN   8192
#define TC    128
#define NCH   65   // 64 cache chunks of 128 + 1 chunk of the 16 new rows
#define LN_EPS 1e-5f
#define RSQRT_D 0.08838834764831845f  // 1/sqrt(128)

// ================= fold reduce: 64-lane partial sums -> one output per lane ==
template<int H>
__device__ __forceinline__ void fold_step(float* v, int lane, int o) {
    bool hi = (lane & o) != 0;
    #pragma unroll
    for (int i = 0; i < H; ++i) {
        float send = hi ? v[i] : v[i + H];
        float keep = hi ? v[i + H] : v[i];
        v[i] = keep + __shfl_xor(send, o);
    }
}

__device__ __forceinline__ void fold64(float* v, int lane) {
    fold_step<32>(v, lane, 32);
    fold_step<16>(v, lane, 16);
    fold_step<8>(v, lane, 8);
    fold_step<4>(v, lane, 4);
    fold_step<2>(v, lane, 2);
    fold_step<1>(v, lane, 1);
}

// ================= split-K GEMV core with W register double-buffer ==========
// Block: 4 waves on the SAME 4 columns; wave w owns k-range [w*K/4,(w+1)*K/4).
// W chunk (HBM stream) for iteration kc+256 is prefetched before the FMA
// block of iteration kc, so the 900-cycle HBM latency hides under ~512 cycles
// of FMA + the other waves. x loads are L2-resident (~200 cy).
template<int KDIM>
__device__ __forceinline__ void gemv_splitk(const float* __restrict__ A,
                                            const float* __restrict__ W,
                                            int col0, int wid, int lane,
                                            float* v) {
    const int kbase = wid * (KDIM / 4);
    const float* wp = W + (size_t)col0 * KDIM + kbase + lane * 4;
    const float* ap = A + kbase + lane * 4;
    float4 wn[4];
    #pragma unroll
    for (int c = 0; c < 4; ++c)
        wn[c] = *(const float4*)(wp + (size_t)c * KDIM);
    #pragma unroll 1
    for (int kc = 0; kc < KDIM / 4; kc += 256) {
        float4 wc[4];
        #pragma unroll
        for (int c = 0; c < 4; ++c) wc[c] = wn[c];
        if (kc + 256 < KDIM / 4) {
            #pragma unroll
            for (int c = 0; c < 4; ++c)
                wn[c] = *(const float4*)(wp + (size_t)c * KDIM + kc + 256);
        }
        #pragma unroll
        for (int m = 0; m < 16; ++m) {
            float4 x4 = *(const float4*)(ap + (size_t)m * KDIM + kc);
            #pragma unroll
            for (int c = 0; c < 4; ++c) {
                v[m * 4 + c] = fmaf(wc[c].x, x4.x, v[m * 4 + c]);
                v[m * 4 + c] = fmaf(wc[c].y, x4.y, v[m * 4 + c]);
                v[m * 4 + c] = fmaf(wc[c].z, x4.z, v[m * 4 + c]);
                v[m * 4 + c] = fmaf(wc[c].w, x4.w, v[m * 4 + c]);
            }
        }
    }
}

__device__ __forceinline__ float crosswave_reduce(float val, int wid, int lane,
                                                  float (*s_red)[64]) {
    if (wid != 0) s_red[wid - 1][lane] = val;
    __syncthreads();
    return val + s_red[0][lane] + s_red[1][lane] + s_red[2][lane];
}

// ---------------- fused QKV GEMV ----------------
__global__ __launch_bounds__(256) void k_qkv(const float* __restrict__ Xn,
                                             const float* __restrict__ Wq,
                                             const float* __restrict__ Wk,
                                             const float* __restrict__ Wv,
                                             float* __restrict__ qws,
                                             float* __restrict__ kws,
                                             float* __restrict__ vws) {
    __shared__ float s_red[3][64];
    int tid = threadIdx.x, wid = tid >> 6, lane = tid & 63;
    int b = blockIdx.x;
    int sel = b >> 9;
    int cb = (b & 511) * 4;
    const float* W = (sel == 0) ? Wq : (sel == 1) ? Wk : Wv;
    float* dst = (sel == 0) ? qws : (sel == 1) ? kws : vws;
    float v[64];
    #pragma unroll
    for (int i = 0; i < 64; ++i) v[i] = 0.f;
    gemv_splitk<2048>(Xn, W, cb, wid, lane, v);
    fold64(v, lane);
    float r = crosswave_reduce(v[0], wid, lane, s_red);
    if (wid == 0) {
        int m = lane >> 2, c = lane & 3;
        int gcol = cb + c;
        int h = gcol >> 7, d = gcol & 127;
        dst[(((size_t)h * 16 + m) << 7) + d] = r;
    }
}

// ---------------- Wup GEMV + gelu ----------------
__device__ __forceinline__ float gelu_exact(float x) {
    return 0.5f * x * (1.0f + erff(x * 0.7071067811865475f));
}

__global__ __launch_bounds__(256) void k_up(const float* __restrict__ A,
                                            const float* __restrict__ W,
                                            float* __restrict__ out) {
    __shared__ float s_red[3][64];
    int tid = threadIdx.x, wid = tid >> 6, lane = tid & 63;
    int cb = blockIdx.x * 4;
    float v[64];
    #pragma unroll
    for (int i = 0; i < 64; ++i) v[i] = 0.f;
    gemv_splitk<2048>(A, W, cb, wid, lane, v);
    fold64(v, lane);
    float r = crosswave_reduce(v[0], wid, lane, s_red);
    if (wid == 0) {
        int m = lane >> 2, c = lane & 3;
        out[(size_t)m * FFN + cb + c] = gelu_exact(r);
    }
}

// ---------------- GEMV + residual ----------------
template<int KDIM>
__global__ __launch_bounds__(256) void k_resid(const float* __restrict__ A,
                                               const float* __restrict__ W,
                                               const float* __restrict__ R,
                                               float* __restrict__ out) {
    __shared__ float s_red[3][64];
    int tid = threadIdx.x, wid = tid >> 6, lane = tid & 63;
    int cb = blockIdx.x * 4;
    float v[64];
    #pragma unroll
    for (int i = 0; i < 64; ++i) v[i] = 0.f;
    gemv_splitk<KDIM>(A, W, cb, wid, lane, v);
    fold64(v, lane);
    float r = crosswave_reduce(v[0], wid, lane, s_red);
    if (wid == 0) {
        int m = lane >> 2, c = lane & 3;
        int col = cb + c;
        out[(size_t)m * NDIM + col] = R[(size_t)m * NDIM + col] + r;
    }
}

// ---------------- LayerNorm: one block per row ----------------
__global__ __launch_bounds__(256) void k_ln(const float* __restrict__ X,
                                            const float* __restrict__ g,
                                            const float* __restrict__ b,
                                            float* __restrict__ out) {
    int row = blockIdx.x, tid = threadIdx.x;
    const float4* xp = (const float4*)(X + (size_t)row * NDIM);
    float4 v0 = xp[tid], v1 = xp[tid + 256];
    float s = v0.x + v0.y + v0.z + v0.w + v1.x + v1.y + v1.z + v1.w;
    float q = v0.x*v0.x + v0.y*v0.y + v0.z*v0.z + v0.w*v0.w
            + v1.x*v1.x + v1.y*v1.y + v1.z*v1.z + v1.w*v1.w;
    #pragma unroll
    for (int o = 32; o; o >>= 1) { s += __shfl_xor(s, o); q += __shfl_xor(q, o); }
    __shared__ float ls[4], lq[4];
    int wid = tid >> 6, lane = tid & 63;
    if (lane == 0) { ls[wid] = s; lq[wid] = q; }
    __syncthreads();
    s = ls[0] + ls[1] + ls[2] + ls[3];
    q = lq[0] + lq[1] + lq[2] + lq[3];
    float mu  = s * (1.f / NDIM);
    float var = q * (1.f / NDIM) - mu * mu;
    float rs  = rsqrtf(var + LN_EPS);
    float4 g0 = ((const float4*)g)[tid], g1 = ((const float4*)g)[tid + 256];
    float4 b0 = ((const float4*)b)[tid], b1 = ((const float4*)b)[tid + 256];
    float4 o0, o1;
    o0.x = (v0.x - mu) * rs * g0.x + b0.x;  o0.y = (v0.y - mu) * rs * g0.y + b0.y;
    o0.z = (v0.z - mu) * rs * g0.z + b0.z;  o0.w = (v0.w - mu) * rs * g0.w + b0.w;
    o1.x = (v1.x - mu) * rs * g1.x + b1.x;  o1.y = (v1.y - mu) * rs * g1.y + b1.y;
    o1.z = (v1.z - mu) * rs * g1.z + b1.z;  o1.w = (v1.w - mu) * rs * g1.w + b1.w;
    float4* op = (float4*)(out + (size_t)row * NDIM);
    op[tid] = o0; op[tid + 256] = o1;
}

// ---------------- attention: block per (head, 128-row chunk) ----------------
// Phase 3 V rows are register double-buffered: batch t+8 loads issue before
// the FMA block of batch t.
__global__ __launch_bounds__(256) void k_attn(const float* __restrict__ cacheK,
                                              const float* __restrict__ cacheV,
                                              const float* __restrict__ qws,
                                              const float* __restrict__ kws,
                                              const float* __restrict__ vws,
                                              float* __restrict__ part,   // [16h][65c][16m][128d]
                                              float* __restrict__ ms) {   // [16h][65c][16m][2]
    __shared__ float s_q[16 * DHEAD];      // 8 KB
    __shared__ float s_p[16][TC];          // 8 KB
    int bid = blockIdx.x;
    int h = bid / NCH, c = bid % NCH;
    int nT = (c < NCH - 1) ? TC : M_TOK;
    const float* Kb = (c < NCH - 1) ? cacheK + ((size_t)h * MAXLEN + (size_t)c * TC) * DHEAD
                                    : kws + (size_t)h * M_TOK * DHEAD;
    const float* Vb = (c < NCH - 1) ? cacheV + ((size_t)h * MAXLEN + (size_t)c * TC) * DHEAD
                                    : vws + (size_t)h * M_TOK * DHEAD;
    int tid = threadIdx.x, wid = tid >> 6, lane = tid & 63;

    // stage q for this head (2048 floats)
    {
        const float4* qp = (const float4*)(qws + (size_t)h * M_TOK * DHEAD);
        float4* sq = (float4*)s_q;
        sq[tid] = qp[tid];
        sq[tid + 256] = qp[tid + 256];
    }
    __syncthreads();

    int tloc = lane & 15, ds = lane >> 4;

    // ---- phase 1: scores, wave handles 32 t rows (two 16-row subtiles) ----
    if (nT == TC) {
        int t0 = wid * 32;
        const float4* kp0 = (const float4*)(Kb + (size_t)(t0 + tloc) * DHEAD + ds * 32);
        const float4* kp1 = (const float4*)(Kb + (size_t)(t0 + 16 + tloc) * DHEAD + ds * 32);
        float4 k0[8], k1[8];
        #pragma unroll
        for (int i = 0; i < 8; ++i) k0[i] = kp0[i];
        #pragma unroll
        for (int i = 0; i < 8; ++i) k1[i] = kp1[i];
        #pragma unroll 4
        for (int m = 0; m < 16; ++m) {
            const float4* qp4 = (const float4*)(s_q + m * DHEAD + ds * 32);
            float a00 = 0.f, a01 = 0.f, a02 = 0.f, a03 = 0.f;
            float a10 = 0.f, a11 = 0.f, a12 = 0.f, a13 = 0.f;
            #pragma unroll
            for (int i = 0; i < 8; ++i) {
                float4 q4 = qp4[i];
                a00 = fmaf(k0[i].x, q4.x, a00); a01 = fmaf(k0[i].y, q4.y, a01);
                a02 = fmaf(k0[i].z, q4.z, a02); a03 = fmaf(k0[i].w, q4.w, a03);
                a10 = fmaf(k1[i].x, q4.x, a10); a11 = fmaf(k1[i].y, q4.y, a11);
                a12 = fmaf(k1[i].z, q4.z, a12); a13 = fmaf(k1[i].w, q4.w, a13);
            }
            float s0 = (a00 + a01) + (a02 + a03);
            float s1 = (a10 + a11) + (a12 + a13);
            s0 += __shfl_xor(s0, 16); s0 += __shfl_xor(s0, 32);
            s1 += __shfl_xor(s1, 16); s1 += __shfl_xor(s1, 32);
            if (lane < 16) {
                s_p[m][t0 + lane]      = s0 * RSQRT_D;
                s_p[m][t0 + 16 + lane] = s1 * RSQRT_D;
            }
        }
    } else if (wid == 0) {   // tail chunk: 16 new rows
        const float4* kp0 = (const float4*)(Kb + (size_t)tloc * DHEAD + ds * 32);
        float4 k0[8];
        #pragma unroll
        for (int i = 0; i < 8; ++i) k0[i] = kp0[i];
        #pragma unroll 4
        for (int m = 0; m < 16; ++m) {
            const float4* qp4 = (const float4*)(s_q + m * DHEAD + ds * 32);
            float a00 = 0.f, a01 = 0.f, a02 = 0.f, a03 = 0.f;
            #pragma unroll
            for (int i = 0; i < 8; ++i) {
                float4 q4 = qp4[i];
                a00 = fmaf(k0[i].x, q4.x, a00); a01 = fmaf(k0[i].y, q4.y, a01);
                a02 = fmaf(k0[i].z, q4.z, a02); a03 = fmaf(k0[i].w, q4.w, a03);
            }
            float s0 = (a00 + a01) + (a02 + a03);
            s0 += __shfl_xor(s0, 16); s0 += __shfl_xor(s0, 32);
            if (lane < 16) s_p[m][lane] = s0 * RSQRT_D;
        }
    }
    __syncthreads();

    // ---- phase 2: chunk-local softmax ----
    int m2 = tid >> 4, tl = tid & 15;
    float mx = -1e30f;
    for (int t = tl; t < nT; t += 16) mx = fmaxf(mx, s_p[m2][t]);
    #pragma unroll
    for (int o = 8; o; o >>= 1) mx = fmaxf(mx, __shfl_xor(mx, o));
    float sm = 0.f;
    for (int t = tl; t < nT; t += 16) {
        float p = expf(s_p[m2][t] - mx);
        s_p[m2][t] = p;
        sm += p;
    }
    #pragma unroll
    for (int o = 8; o; o >>= 1) sm += __shfl_xor(sm, o);
    if (tl == 0) {
        float* msp = ms + ((size_t)(h * NCH + c) * 16 + m2) * 2;
        msp[0] = mx; msp[1] = sm;
    }
    __syncthreads();

    // ---- phase 3: partial PV, 8-t tiles, V register double-buffered ----
    int mg = wid * 4;
    float2 acc2[4] = {{0.f,0.f},{0.f,0.f},{0.f,0.f},{0.f,0.f}};
    float2 vn[8];
    #pragma unroll
    for (int i = 0; i < 8; ++i)
        vn[i] = *(const float2*)(Vb + (size_t)i * DHEAD + 2 * lane);
    for (int t = 0; t < nT; t += 8) {
        float2 vv[8];
        #pragma unroll
        for (int i = 0; i < 8; ++i) vv[i] = vn[i];
        if (t + 8 < nT) {
            #pragma unroll
            for (int i = 0; i < 8; ++i)
                vn[i] = *(const float2*)(Vb + (size_t)(t + 8 + i) * DHEAD + 2 * lane);
        }
        float4 p0[4], p1[4];
        #pragma unroll
        for (int mm = 0; mm < 4; ++mm) {
            p0[mm] = *(const float4*)&s_p[mg + mm][t];
            p1[mm] = *(const float4*)&s_p[mg + mm][t + 4];
        }
        #pragma unroll
        for (int mm = 0; mm < 4; ++mm) {
            acc2[mm].x = fmaf(p0[mm].x, vv[0].x, acc2[mm].x);
            acc2[mm].y = fmaf(p0[mm].x, vv[0].y, acc2[mm].y);
            acc2[mm].x = fmaf(p0[mm].y, vv[1].x, acc2[mm].x);
            acc2[mm].y = fmaf(p0[mm].y, vv[1].y, acc2[mm].y);
            acc2[mm].x = fmaf(p0[mm].z, vv[2].x, acc2[mm].x);
            acc2[mm].y = fmaf(p0[mm].z, vv[2].y, acc2[mm].y);
            acc2[mm].x = fmaf(p0[mm].w, vv[3].x, acc2[mm].x);
            acc2[mm].y = fmaf(p0[mm].w, vv[3].y, acc2[mm].y);
            acc2[mm].x = fmaf(p1[mm].x, vv[4].x, acc2[mm].x);
            acc2[mm].y = fmaf(p1[mm].x, vv[4].y, acc2[mm].y);
            acc2[mm].x = fmaf(p1[mm].y, vv[5].x, acc2[mm].x);
            acc2[mm].y = fmaf(p1[mm].y, vv[5].y, acc2[mm].y);
            acc2[mm].x = fmaf(p1[mm].z, vv[6].x, acc2[mm].x);
            acc2[mm].y = fmaf(p1[mm].z, vv[6].y, acc2[mm].y);
            acc2[mm].x = fmaf(p1[mm].w, vv[7].x, acc2[mm].x);
            acc2[mm].y = fmaf(p1[mm].w, vv[7].y, acc2[mm].y);
        }
    }
    #pragma unroll
    for (int mm = 0; mm < 4; ++mm) {
        float* dp = part + ((size_t)(h * NCH + c) * 16 + mg + mm) * DHEAD + 2 * lane;
        dp[0] = acc2[mm].x; dp[1] = acc2[mm].y;
    }
}

// ---------------- combine chunk partials: block per (head, 16-d slice) -------
__global__ __launch_bounds__(256) void k_combine(const float* __restrict__ part,
                                                 const float* __restrict__ ms,
                                                 float* __restrict__ attnout) {
    __shared__ float scale[16][NCH];
    int h = blockIdx.x >> 3, dblk = blockIdx.x & 7;
    int tid = threadIdx.x;
    if (tid < 16) {
        int m = tid;
        float gmax = -1e30f;
        for (int c = 0; c < NCH; ++c)
            gmax = fmaxf(gmax, ms[((size_t)(h * NCH + c) * 16 + m) * 2]);
        float denom = 0.f;
        for (int c = 0; c < NCH; ++c) {
            const float* msp = ms + ((size_t)(h * NCH + c) * 16 + m) * 2;
            denom += msp[1] * expf(msp[0] - gmax);
        }
        float inv = 1.f / denom;
        for (int c = 0; c < NCH; ++c) {
            const float* msp = ms + ((size_t)(h * NCH + c) * 16 + m) * 2;
            scale[m][c] = expf(msp[0] - gmax) * inv;
        }
    }
    __syncthreads();
    int m = tid >> 4, dd = tid & 15;
    int d = dblk * 16 + dd;
    const float* pp = part + ((size_t)h * NCH * 16 + m) * DHEAD + d;
    float acc = 0.f;
    for (int c = 0; c < NCH; ++c)
        acc = fmaf(pp[(size_t)c * 16 * DHEAD], scale[m][c], acc);
    attnout[(size_t)m * NDIM + h * DHEAD + d] = acc;
}

// ---------------- launcher ----------------
extern "C" void kernel_launch(void* const* d_in, const int* in_sizes, int n_in,
                              void* d_out, int out_size, void* d_ws, size_t ws_size,
                              hipStream_t stream) {
    const float* X      = (const float*)d_in[0];
    const float* ln1_g  = (const float*)d_in[1];
    const float* ln1_b  = (const float*)d_in[2];
    const float* Wq     = (const float*)d_in[3];
    const float* Wk     = (const float*)d_in[4];
    const float* Wv     = (const float*)d_in[5];
    const float* Wo     = (const float*)d_in[6];
    const float* ln2_g  = (const float*)d_in[7];
    const float* ln2_b  = (const float*)d_in[8];
    const float* Wup    = (const float*)d_in[9];
    const float* Wdown  = (const float*)d_in[10];
    const float* cacheK = (const float*)d_in[11];
    const float* cacheV = (const float*)d_in[12];
    float* out = (float*)d_out;

    float* ws = (float*)d_ws;
    float* Xn1    = ws;                       // 32768
    float* qws    = Xn1 + 32768;              // 32768
    float* kws    = qws + 32768;              // 32768
    float* vws    = kws + 32768;              // 32768
    float* partb  = vws + 32768;              // 16*65*16*128 = 2129920
    float* msb    = partb + 2129920;          // 16*65*16*2   = 33280
    float* attn_o = msb + 33280;              // 32768
    float* X2     = attn_o + 32768;           // 32768
    float* Xn2    = X2 + 32768;               // 32768
    float* ffnh   = Xn2 + 32768;              // 131072

    k_ln<<<M_TOK, 256, 0, stream>>>(X, ln1_g, ln1_b, Xn1);
    k_qkv<<<1536, 256, 0, stream>>>(Xn1, Wq, Wk, Wv, qws, kws, vws);
    k_attn<<<NHEAD * NCH, 256, 0, stream>>>(cacheK, cacheV, qws, kws, vws, partb, msb);
    k_combine<<<NHEAD * 8, 256, 0, stream>>>(partb, msb, attn_o);
    k_resid<2048><<<512, 256, 0, stream>>>(attn_o, Wo, X, X2);
    k_ln<<<M_TOK, 256, 0, stream>>>(X2, ln2_g, ln2_b, Xn2);
    k_up<<<2048, 256, 0, stream>>>(Xn2, Wup, ffnh);
    k_resid<8192><<<512, 256, 0, stream>>>(ffnh, Wdown, X2, out);
}

// Round 6
// 194.274 us; speedup vs baseline: 1.0025x; 1.0025x over previous
//
#include <hip/hip_runtime.h>
#include <hip/hip_bf16.h>
#include <math.h>

#define M_TOK 16
#define NDIM  2048
#define DHEAD 128
#define NHEAD 16
#define MAXLEN 8448
#define FFN   8192
#define TC    64
#define NCH   133  // 132 cache chunks of 64 + 1 chunk of the 16 new rows
#define LN_EPS 1e-5f
#define RSQRT_D 0.08838834764831845f  // 1/sqrt(128)

// ================= fold reduce: 64-lane partial sums -> one output per lane ==
template<int H>
__device__ __forceinline__ void fold_step(float* v, int lane, int o) {
    bool hi = (lane & o) != 0;
    #pragma unroll
    for (int i = 0; i < H; ++i) {
        float send = hi ? v[i] : v[i + H];
        float keep = hi ? v[i + H] : v[i];
        v[i] = keep + __shfl_xor(send, o);
    }
}

__device__ __forceinline__ void fold64(float* v, int lane) {
    fold_step<32>(v, lane, 32);
    fold_step<16>(v, lane, 16);
    fold_step<8>(v, lane, 8);
    fold_step<4>(v, lane, 4);
    fold_step<2>(v, lane, 2);
    fold_step<1>(v, lane, 1);
}

// After fold32: lane L holds the all-lane sum of v[(L>>1)&31] (pairs duplicate).
__device__ __forceinline__ void fold32(float* v, int lane) {
    fold_step<16>(v, lane, 32);
    fold_step<8>(v, lane, 16);
    fold_step<4>(v, lane, 8);
    fold_step<2>(v, lane, 4);
    fold_step<1>(v, lane, 2);
    v[0] += __shfl_xor(v[0], 1);
}

// ================= split-K GEMV core (R3 form — plain loads) =================
// Block: 4 waves on the SAME cols; wave w owns k-range [w*K/4,(w+1)*K/4).
// All loads fully coalesced (1KB/instr).
template<int KDIM>
__device__ __forceinline__ void gemv_splitk(const float* __restrict__ A,
                                            const float* __restrict__ W,
                                            int col0, int wid, int lane,
                                            float* v) {
    const int kbase = wid * (KDIM / 4);
    const float* wp = W + (size_t)col0 * KDIM + kbase + lane * 4;
    const float* ap = A + kbase + lane * 4;
    #pragma unroll 1
    for (int kc = 0; kc < KDIM / 4; kc += 256) {
        float4 w4[4];
        #pragma unroll
        for (int c = 0; c < 4; ++c)
            w4[c] = *(const float4*)(wp + (size_t)c * KDIM + kc);
        #pragma unroll
        for (int m = 0; m < 16; ++m) {
            float4 x4 = *(const float4*)(ap + (size_t)m * KDIM + kc);
            #pragma unroll
            for (int c = 0; c < 4; ++c) {
                v[m * 4 + c] = fmaf(w4[c].x, x4.x, v[m * 4 + c]);
                v[m * 4 + c] = fmaf(w4[c].y, x4.y, v[m * 4 + c]);
                v[m * 4 + c] = fmaf(w4[c].z, x4.z, v[m * 4 + c]);
                v[m * 4 + c] = fmaf(w4[c].w, x4.w, v[m * 4 + c]);
            }
        }
    }
}

// 2-column variant (v[32] accumulator -> lower VGPR, 2x more blocks)
template<int KDIM>
__device__ __forceinline__ void gemv_splitk2(const float* __restrict__ A,
                                             const float* __restrict__ W,
                                             int col0, int wid, int lane,
                                             float* v) {
    const int kbase = wid * (KDIM / 4);
    const float* wp = W + (size_t)col0 * KDIM + kbase + lane * 4;
    const float* ap = A + kbase + lane * 4;
    #pragma unroll 1
    for (int kc = 0; kc < KDIM / 4; kc += 256) {
        float4 w4[2];
        #pragma unroll
        for (int c = 0; c < 2; ++c)
            w4[c] = *(const float4*)(wp + (size_t)c * KDIM + kc);
        #pragma unroll
        for (int m = 0; m < 16; ++m) {
            float4 x4 = *(const float4*)(ap + (size_t)m * KDIM + kc);
            #pragma unroll
            for (int c = 0; c < 2; ++c) {
                v[m * 2 + c] = fmaf(w4[c].x, x4.x, v[m * 2 + c]);
                v[m * 2 + c] = fmaf(w4[c].y, x4.y, v[m * 2 + c]);
                v[m * 2 + c] = fmaf(w4[c].z, x4.z, v[m * 2 + c]);
                v[m * 2 + c] = fmaf(w4[c].w, x4.w, v[m * 2 + c]);
            }
        }
    }
}

__device__ __forceinline__ float crosswave_reduce(float val, int wid, int lane,
                                                  float (*s_red)[64]) {
    if (wid != 0) s_red[wid - 1][lane] = val;
    __syncthreads();
    return val + s_red[0][lane] + s_red[1][lane] + s_red[2][lane];
}

// ---------------- fused QKV GEMV ----------------
__global__ __launch_bounds__(256) void k_qkv(const float* __restrict__ Xn,
                                             const float* __restrict__ Wq,
                                             const float* __restrict__ Wk,
                                             const float* __restrict__ Wv,
                                             float* __restrict__ qws,
                                             float* __restrict__ kws,
                                             float* __restrict__ vws) {
    __shared__ float s_red[3][64];
    int tid = threadIdx.x, wid = tid >> 6, lane = tid & 63;
    int b = blockIdx.x;
    int sel = b >> 9;
    int cb = (b & 511) * 4;
    const float* W = (sel == 0) ? Wq : (sel == 1) ? Wk : Wv;
    float* dst = (sel == 0) ? qws : (sel == 1) ? kws : vws;
    float v[64];
    #pragma unroll
    for (int i = 0; i < 64; ++i) v[i] = 0.f;
    gemv_splitk<2048>(Xn, W, cb, wid, lane, v);
    fold64(v, lane);
    float r = crosswave_reduce(v[0], wid, lane, s_red);
    if (wid == 0) {
        int m = lane >> 2, c = lane & 3;
        int gcol = cb + c;
        int h = gcol >> 7, d = gcol & 127;
        dst[(((size_t)h * 16 + m) << 7) + d] = r;
    }
}

// ---------------- Wup GEMV + gelu ----------------
__device__ __forceinline__ float gelu_exact(float x) {
    return 0.5f * x * (1.0f + erff(x * 0.7071067811865475f));
}

__global__ __launch_bounds__(256) void k_up(const float* __restrict__ A,
                                            const float* __restrict__ W,
                                            float* __restrict__ out) {
    __shared__ float s_red[3][64];
    int tid = threadIdx.x, wid = tid >> 6, lane = tid & 63;
    int cb = blockIdx.x * 4;
    float v[64];
    #pragma unroll
    for (int i = 0; i < 64; ++i) v[i] = 0.f;
    gemv_splitk<2048>(A, W, cb, wid, lane, v);
    fold64(v, lane);
    float r = crosswave_reduce(v[0], wid, lane, s_red);
    if (wid == 0) {
        int m = lane >> 2, c = lane & 3;
        out[(size_t)m * FFN + cb + c] = gelu_exact(r);
    }
}

// ---------------- GEMV + residual (2 cols/block) ----------------
template<int KDIM>
__global__ __launch_bounds__(256) void k_resid(const float* __restrict__ A,
                                               const float* __restrict__ W,
                                               const float* __restrict__ R,
                                               float* __restrict__ out) {
    __shared__ float s_red[3][64];
    int tid = threadIdx.x, wid = tid >> 6, lane = tid & 63;
    int cb = blockIdx.x * 2;               // 1024 blocks -> 2048 cols
    float v[32];
    #pragma unroll
    for (int i = 0; i < 32; ++i) v[i] = 0.f;
    gemv_splitk2<KDIM>(A, W, cb, wid, lane, v);
    fold32(v, lane);
    float r = crosswave_reduce(v[0], wid, lane, s_red);
    if (wid == 0 && (lane & 1) == 0) {
        int idx = (lane >> 1) & 31;
        int m = idx >> 1, c = idx & 1;
        int col = cb + c;
        out[(size_t)m * NDIM + col] = R[(size_t)m * NDIM + col] + r;
    }
}

// ---------------- LayerNorm: one block per row ----------------
__global__ __launch_bounds__(256) void k_ln(const float* __restrict__ X,
                                            const float* __restrict__ g,
                                            const float* __restrict__ b,
                                            float* __restrict__ out) {
    int row = blockIdx.x, tid = threadIdx.x;
    const float4* xp = (const float4*)(X + (size_t)row * NDIM);
    float4 v0 = xp[tid], v1 = xp[tid + 256];
    float s = v0.x + v0.y + v0.z + v0.w + v1.x + v1.y + v1.z + v1.w;
    float q = v0.x*v0.x + v0.y*v0.y + v0.z*v0.z + v0.w*v0.w
            + v1.x*v1.x + v1.y*v1.y + v1.z*v1.z + v1.w*v1.w;
    #pragma unroll
    for (int o = 32; o; o >>= 1) { s += __shfl_xor(s, o); q += __shfl_xor(q, o); }
    __shared__ float ls[4], lq[4];
    int wid = tid >> 6, lane = tid & 63;
    if (lane == 0) { ls[wid] = s; lq[wid] = q; }
    __syncthreads();
    s = ls[0] + ls[1] + ls[2] + ls[3];
    q = lq[0] + lq[1] + lq[2] + lq[3];
    float mu  = s * (1.f / NDIM);
    float var = q * (1.f / NDIM) - mu * mu;
    float rs  = rsqrtf(var + LN_EPS);
    float4 g0 = ((const float4*)g)[tid], g1 = ((const float4*)g)[tid + 256];
    float4 b0 = ((const float4*)b)[tid], b1 = ((const float4*)b)[tid + 256];
    float4 o0, o1;
    o0.x = (v0.x - mu) * rs * g0.x + b0.x;  o0.y = (v0.y - mu) * rs * g0.y + b0.y;
    o0.z = (v0.z - mu) * rs * g0.z + b0.z;  o0.w = (v0.w - mu) * rs * g0.w + b0.w;
    o1.x = (v1.x - mu) * rs * g1.x + b1.x;  o1.y = (v1.y - mu) * rs * g1.y + b1.y;
    o1.z = (v1.z - mu) * rs * g1.z + b1.z;  o1.w = (v1.w - mu) * rs * g1.w + b1.w;
    float4* op = (float4*)(out + (size_t)row * NDIM);
    op[tid] = o0; op[tid + 256] = o1;
}

// ---------------- attention: block per (head, 64-row chunk) ----------------
// TC=64: 2128 blocks (~8.3/CU, wave-slot limit) so co-resident blocks are
// mutually out of phase and keep both HBM and VALU fed.
__global__ __launch_bounds__(256) void k_attn(const float* __restrict__ cacheK,
                                              const float* __restrict__ cacheV,
                                              const float* __restrict__ qws,
                                              const float* __restrict__ kws,
                                              const float* __restrict__ vws,
                                              float* __restrict__ part,   // [16h][133c][16m][128d]
                                              float* __restrict__ ms) {   // [16h][133c][16m][2]
    __shared__ float s_q[16 * DHEAD];      // 8 KB
    __shared__ float s_p[16][TC];          // 4 KB
    int bid = blockIdx.x;
    int h = bid / NCH, c = bid % NCH;
    int nT = (c < NCH - 1) ? TC : M_TOK;
    const float* Kb = (c < NCH - 1) ? cacheK + ((size_t)h * MAXLEN + (size_t)c * TC) * DHEAD
                                    : kws + (size_t)h * M_TOK * DHEAD;
    const float* Vb = (c < NCH - 1) ? cacheV + ((size_t)h * MAXLEN + (size_t)c * TC) * DHEAD
                                    : vws + (size_t)h * M_TOK * DHEAD;
    int tid = threadIdx.x, wid = tid >> 6, lane = tid & 63;

    // stage q for this head (2048 floats)
    {
        const float4* qp = (const float4*)(qws + (size_t)h * M_TOK * DHEAD);
        float4* sq = (float4*)s_q;
        sq[tid] = qp[tid];
        sq[tid + 256] = qp[tid + 256];
    }
    __syncthreads();

    int tloc = lane & 15, ds = lane >> 4;

    // ---- phase 1: scores; wave wid handles rows [wid*16, wid*16+16) ----
    if (nT == TC || wid == 0) {
        int t0 = (nT == TC) ? wid * 16 : 0;
        const float4* kp0 = (const float4*)(Kb + (size_t)(t0 + tloc) * DHEAD + ds * 32);
        float4 k0[8];
        #pragma unroll
        for (int i = 0; i < 8; ++i) k0[i] = kp0[i];
        #pragma unroll 4
        for (int m = 0; m < 16; ++m) {
            const float4* qp4 = (const float4*)(s_q + m * DHEAD + ds * 32);
            float a00 = 0.f, a01 = 0.f, a02 = 0.f, a03 = 0.f;
            #pragma unroll
            for (int i = 0; i < 8; ++i) {
                float4 q4 = qp4[i];
                a00 = fmaf(k0[i].x, q4.x, a00); a01 = fmaf(k0[i].y, q4.y, a01);
                a02 = fmaf(k0[i].z, q4.z, a02); a03 = fmaf(k0[i].w, q4.w, a03);
            }
            float s0 = (a00 + a01) + (a02 + a03);
            s0 += __shfl_xor(s0, 16); s0 += __shfl_xor(s0, 32);
            if (lane < 16) s_p[m][t0 + lane] = s0 * RSQRT_D;
        }
    }
    __syncthreads();

    // ---- phase 2: chunk-local softmax (16 lanes per m-row) ----
    int m2 = tid >> 4, tl = tid & 15;
    float mx = -1e30f;
    for (int t = tl; t < nT; t += 16) mx = fmaxf(mx, s_p[m2][t]);
    #pragma unroll
    for (int o = 8; o; o >>= 1) mx = fmaxf(mx, __shfl_xor(mx, o));
    float sm = 0.f;
    for (int t = tl; t < nT; t += 16) {
        float p = expf(s_p[m2][t] - mx);
        s_p[m2][t] = p;
        sm += p;
    }
    #pragma unroll
    for (int o = 8; o; o >>= 1) sm += __shfl_xor(sm, o);
    if (tl == 0) {
        float* msp = ms + ((size_t)(h * NCH + c) * 16 + m2) * 2;
        msp[0] = mx; msp[1] = sm;
    }
    __syncthreads();

    // ---- phase 3: partial PV, 8-t tiles; wave handles 4 m ----
    int mg = wid * 4;
    float2 acc2[4] = {{0.f,0.f},{0.f,0.f},{0.f,0.f},{0.f,0.f}};
    for (int t = 0; t < nT; t += 8) {
        float2 vv[8];
        #pragma unroll
        for (int i = 0; i < 8; ++i)
            vv[i] = *(const float2*)(Vb + (size_t)(t + i) * DHEAD + 2 * lane);
        float4 p0[4], p1[4];
        #pragma unroll
        for (int mm = 0; mm < 4; ++mm) {
            p0[mm] = *(const float4*)&s_p[mg + mm][t];
            p1[mm] = *(const float4*)&s_p[mg + mm][t + 4];
        }
        #pragma unroll
        for (int mm = 0; mm < 4; ++mm) {
            acc2[mm].x = fmaf(p0[mm].x, vv[0].x, acc2[mm].x);
            acc2[mm].y = fmaf(p0[mm].x, vv[0].y, acc2[mm].y);
            acc2[mm].x = fmaf(p0[mm].y, vv[1].x, acc2[mm].x);
            acc2[mm].y = fmaf(p0[mm].y, vv[1].y, acc2[mm].y);
            acc2[mm].x = fmaf(p0[mm].z, vv[2].x, acc2[mm].x);
            acc2[mm].y = fmaf(p0[mm].z, vv[2].y, acc2[mm].y);
            acc2[mm].x = fmaf(p0[mm].w, vv[3].x, acc2[mm].x);
            acc2[mm].y = fmaf(p0[mm].w, vv[3].y, acc2[mm].y);
            acc2[mm].x = fmaf(p1[mm].x, vv[4].x, acc2[mm].x);
            acc2[mm].y = fmaf(p1[mm].x, vv[4].y, acc2[mm].y);
            acc2[mm].x = fmaf(p1[mm].y, vv[5].x, acc2[mm].x);
            acc2[mm].y = fmaf(p1[mm].y, vv[5].y, acc2[mm].y);
            acc2[mm].x = fmaf(p1[mm].z, vv[6].x, acc2[mm].x);
            acc2[mm].y = fmaf(p1[mm].z, vv[6].y, acc2[mm].y);
            acc2[mm].x = fmaf(p1[mm].w, vv[7].x, acc2[mm].x);
            acc2[mm].y = fmaf(p1[mm].w, vv[7].y, acc2[mm].y);
        }
    }
    #pragma unroll
    for (int mm = 0; mm < 4; ++mm) {
        float* dp = part + ((size_t)(h * NCH + c) * 16 + mg + mm) * DHEAD + 2 * lane;
        dp[0] = acc2[mm].x; dp[1] = acc2[mm].y;
    }
}

// ---------------- combine chunk partials: block per (head, 16-d slice) -------
__global__ __launch_bounds__(256) void k_combine(const float* __restrict__ part,
                                                 const float* __restrict__ ms,
                                                 float* __restrict__ attnout) {
    __shared__ float scale[16][NCH];
    int h = blockIdx.x >> 3, dblk = blockIdx.x & 7;
    int tid = threadIdx.x;
    if (tid < 16) {
        int m = tid;
        float gmax = -1e30f;
        for (int c = 0; c < NCH; ++c)
            gmax = fmaxf(gmax, ms[((size_t)(h * NCH + c) * 16 + m) * 2]);
        float denom = 0.f;
        for (int c = 0; c < NCH; ++c) {
            const float* msp = ms + ((size_t)(h * NCH + c) * 16 + m) * 2;
            denom += msp[1] * expf(msp[0] - gmax);
        }
        float inv = 1.f / denom;
        for (int c = 0; c < NCH; ++c) {
            const float* msp = ms + ((size_t)(h * NCH + c) * 16 + m) * 2;
            scale[m][c] = expf(msp[0] - gmax) * inv;
        }
    }
    __syncthreads();
    int m = tid >> 4, dd = tid & 15;
    int d = dblk * 16 + dd;
    const float* pp = part + ((size_t)h * NCH * 16 + m) * DHEAD + d;
    float acc = 0.f;
    for (int c = 0; c < NCH; ++c)
        acc = fmaf(pp[(size_t)c * 16 * DHEAD], scale[m][c], acc);
    attnout[(size_t)m * NDIM + h * DHEAD + d] = acc;
}

// ---------------- launcher ----------------
extern "C" void kernel_launch(void* const* d_in, const int* in_sizes, int n_in,
                              void* d_out, int out_size, void* d_ws, size_t ws_size,
                              hipStream_t stream) {
    const float* X      = (const float*)d_in[0];
    const float* ln1_g  = (const float*)d_in[1];
    const float* ln1_b  = (const float*)d_in[2];
    const float* Wq     = (const float*)d_in[3];
    const float* Wk     = (const float*)d_in[4];
    const float* Wv     = (const float*)d_in[5];
    const float* Wo     = (const float*)d_in[6];
    const float* ln2_g  = (const float*)d_in[7];
    const float* ln2_b  = (const float*)d_in[8];
    const float* Wup    = (const float*)d_in[9];
    const float* Wdown  = (const float*)d_in[10];
    const float* cacheK = (const float*)d_in[11];
    const float* cacheV = (const float*)d_in[12];
    float* out = (float*)d_out;

    float* ws = (float*)d_ws;
    float* Xn1    = ws;                       // 32768
    float* qws    = Xn1 + 32768;              // 32768
    float* kws    = qws + 32768;              // 32768
    float* vws    = kws + 32768;              // 32768
    float* partb  = vws + 32768;              // 16*133*16*128 = 4358144
    float* msb    = partb + 4358144;          // 16*133*16*2   = 68096
    float* attn_o = msb + 68096;              // 32768
    float* X2     = attn_o + 32768;           // 32768
    float* Xn2    = X2 + 32768;               // 32768
    float* ffnh   = Xn2 + 32768;              // 131072

    k_ln<<<M_TOK, 256, 0, stream>>>(X, ln1_g, ln1_b, Xn1);
    k_qkv<<<1536, 256, 0, stream>>>(Xn1, Wq, Wk, Wv, qws, kws, vws);
    k_attn<<<NHEAD * NCH, 256, 0, stream>>>(cacheK, cacheV, qws, kws, vws, partb, msb);
    k_combine<<<NHEAD * 8, 256, 0, stream>>>(partb, msb, attn_o);
    k_resid<2048><<<1024, 256, 0, stream>>>(attn_o, Wo, X, X2);
    k_ln<<<M_TOK, 256, 0, stream>>>(X2, ln2_g, ln2_b, Xn2);
    k_up<<<2048, 256, 0, stream>>>(Xn2, Wup, ffnh);
    k_resid<8192><<<1024, 256, 0, stream>>>(ffnh, Wdown, X2, out);
}

// Round 7
// 179.868 us; speedup vs baseline: 1.0828x; 1.0801x over previous
//
#include <hip/hip_runtime.h>
#include <hip/hip_bf16.h>
#include <math.h>

#define M_TOK 16
#define NDIM  2048
#define DHEAD 128
#define NHEAD 16
#define MAXLEN 8448
#define FFN   8192
#define TC    64
#define NCH   129  // 128 cache chunks of 64 + 1 chunk of the 16 new rows
#define LN_EPS 1e-5f
#define RSQRT_D 0.08838834764831845f  // 1/sqrt(128)

// ================= fold reduce: 64-lane partial sums -> one output per lane ==
template<int H>
__device__ __forceinline__ void fold_step(float* v, int lane, int o) {
    bool hi = (lane & o) != 0;
    #pragma unroll
    for (int i = 0; i < H; ++i) {
        float send = hi ? v[i] : v[i + H];
        float keep = hi ? v[i + H] : v[i];
        v[i] = keep + __shfl_xor(send, o);
    }
}

__device__ __forceinline__ void fold64(float* v, int lane) {
    fold_step<32>(v, lane, 32);
    fold_step<16>(v, lane, 16);
    fold_step<8>(v, lane, 8);
    fold_step<4>(v, lane, 4);
    fold_step<2>(v, lane, 2);
    fold_step<1>(v, lane, 1);
}

__device__ __forceinline__ void fold32(float* v, int lane) {
    fold_step<16>(v, lane, 32);
    fold_step<8>(v, lane, 16);
    fold_step<4>(v, lane, 8);
    fold_step<2>(v, lane, 4);
    fold_step<1>(v, lane, 2);
    v[0] += __shfl_xor(v[0], 1);
}

// ================= split-K GEMV core (R3 form — plain loads) =================
template<int KDIM>
__device__ __forceinline__ void gemv_splitk(const float* __restrict__ A,
                                            const float* __restrict__ W,
                                            int col0, int wid, int lane,
                                            float* v) {
    const int kbase = wid * (KDIM / 4);
    const float* wp = W + (size_t)col0 * KDIM + kbase + lane * 4;
    const float* ap = A + kbase + lane * 4;
    #pragma unroll 1
    for (int kc = 0; kc < KDIM / 4; kc += 256) {
        float4 w4[4];
        #pragma unroll
        for (int c = 0; c < 4; ++c)
            w4[c] = *(const float4*)(wp + (size_t)c * KDIM + kc);
        #pragma unroll
        for (int m = 0; m < 16; ++m) {
            float4 x4 = *(const float4*)(ap + (size_t)m * KDIM + kc);
            #pragma unroll
            for (int c = 0; c < 4; ++c) {
                v[m * 4 + c] = fmaf(w4[c].x, x4.x, v[m * 4 + c]);
                v[m * 4 + c] = fmaf(w4[c].y, x4.y, v[m * 4 + c]);
                v[m * 4 + c] = fmaf(w4[c].z, x4.z, v[m * 4 + c]);
                v[m * 4 + c] = fmaf(w4[c].w, x4.w, v[m * 4 + c]);
            }
        }
    }
}

template<int KDIM>
__device__ __forceinline__ void gemv_splitk2(const float* __restrict__ A,
                                             const float* __restrict__ W,
                                             int col0, int wid, int lane,
                                             float* v) {
    const int kbase = wid * (KDIM / 4);
    const float* wp = W + (size_t)col0 * KDIM + kbase + lane * 4;
    const float* ap = A + kbase + lane * 4;
    #pragma unroll 1
    for (int kc = 0; kc < KDIM / 4; kc += 256) {
        float4 w4[2];
        #pragma unroll
        for (int c = 0; c < 2; ++c)
            w4[c] = *(const float4*)(wp + (size_t)c * KDIM + kc);
        #pragma unroll
        for (int m = 0; m < 16; ++m) {
            float4 x4 = *(const float4*)(ap + (size_t)m * KDIM + kc);
            #pragma unroll
            for (int c = 0; c < 2; ++c) {
                v[m * 2 + c] = fmaf(w4[c].x, x4.x, v[m * 2 + c]);
                v[m * 2 + c] = fmaf(w4[c].y, x4.y, v[m * 2 + c]);
                v[m * 2 + c] = fmaf(w4[c].z, x4.z, v[m * 2 + c]);
                v[m * 2 + c] = fmaf(w4[c].w, x4.w, v[m * 2 + c]);
            }
        }
    }
}

__device__ __forceinline__ float crosswave_reduce(float val, int wid, int lane,
                                                  float (*s_red)[64]) {
    if (wid != 0) s_red[wid - 1][lane] = val;
    __syncthreads();
    return val + s_red[0][lane] + s_red[1][lane] + s_red[2][lane];
}

// ---------------- fused QKV GEMV ----------------
__global__ __launch_bounds__(256) void k_qkv(const float* __restrict__ Xn,
                                             const float* __restrict__ Wq,
                                             const float* __restrict__ Wk,
                                             const float* __restrict__ Wv,
                                             float* __restrict__ qws,
                                             float* __restrict__ kws,
                                             float* __restrict__ vws) {
    __shared__ float s_red[3][64];
    int tid = threadIdx.x, wid = tid >> 6, lane = tid & 63;
    int b = blockIdx.x;
    int sel = b >> 9;
    int cb = (b & 511) * 4;
    const float* W = (sel == 0) ? Wq : (sel == 1) ? Wk : Wv;
    float* dst = (sel == 0) ? qws : (sel == 1) ? kws : vws;
    float v[64];
    #pragma unroll
    for (int i = 0; i < 64; ++i) v[i] = 0.f;
    gemv_splitk<2048>(Xn, W, cb, wid, lane, v);
    fold64(v, lane);
    float r = crosswave_reduce(v[0], wid, lane, s_red);
    if (wid == 0) {
        int m = lane >> 2, c = lane & 3;
        int gcol = cb + c;
        int h = gcol >> 7, d = gcol & 127;
        dst[(((size_t)h * 16 + m) << 7) + d] = r;
    }
}

// ---------------- Wup GEMV + gelu ----------------
__device__ __forceinline__ float gelu_exact(float x) {
    return 0.5f * x * (1.0f + erff(x * 0.7071067811865475f));
}

__global__ __launch_bounds__(256) void k_up(const float* __restrict__ A,
                                            const float* __restrict__ W,
                                            float* __restrict__ out) {
    __shared__ float s_red[3][64];
    int tid = threadIdx.x, wid = tid >> 6, lane = tid & 63;
    int cb = blockIdx.x * 4;
    float v[64];
    #pragma unroll
    for (int i = 0; i < 64; ++i) v[i] = 0.f;
    gemv_splitk<2048>(A, W, cb, wid, lane, v);
    fold64(v, lane);
    float r = crosswave_reduce(v[0], wid, lane, s_red);
    if (wid == 0) {
        int m = lane >> 2, c = lane & 3;
        out[(size_t)m * FFN + cb + c] = gelu_exact(r);
    }
}

// ---------------- GEMV + residual (2 cols/block) ----------------
template<int KDIM>
__global__ __launch_bounds__(256) void k_resid(const float* __restrict__ A,
                                               const float* __restrict__ W,
                                               const float* __restrict__ R,
                                               float* __restrict__ out) {
    __shared__ float s_red[3][64];
    int tid = threadIdx.x, wid = tid >> 6, lane = tid & 63;
    int cb = blockIdx.x * 2;
    float v[32];
    #pragma unroll
    for (int i = 0; i < 32; ++i) v[i] = 0.f;
    gemv_splitk2<KDIM>(A, W, cb, wid, lane, v);
    fold32(v, lane);
    float r = crosswave_reduce(v[0], wid, lane, s_red);
    if (wid == 0 && (lane & 1) == 0) {
        int idx = (lane >> 1) & 31;
        int m = idx >> 1, c = idx & 1;
        int col = cb + c;
        out[(size_t)m * NDIM + col] = R[(size_t)m * NDIM + col] + r;
    }
}

// ---------------- LayerNorm: one block per row ----------------
__global__ __launch_bounds__(256) void k_ln(const float* __restrict__ X,
                                            const float* __restrict__ g,
                                            const float* __restrict__ b,
                                            float* __restrict__ out) {
    int row = blockIdx.x, tid = threadIdx.x;
    const float4* xp = (const float4*)(X + (size_t)row * NDIM);
    float4 v0 = xp[tid], v1 = xp[tid + 256];
    float s = v0.x + v0.y + v0.z + v0.w + v1.x + v1.y + v1.z + v1.w;
    float q = v0.x*v0.x + v0.y*v0.y + v0.z*v0.z + v0.w*v0.w
            + v1.x*v1.x + v1.y*v1.y + v1.z*v1.z + v1.w*v1.w;
    #pragma unroll
    for (int o = 32; o; o >>= 1) { s += __shfl_xor(s, o); q += __shfl_xor(q, o); }
    __shared__ float ls[4], lq[4];
    int wid = tid >> 6, lane = tid & 63;
    if (lane == 0) { ls[wid] = s; lq[wid] = q; }
    __syncthreads();
    s = ls[0] + ls[1] + ls[2] + ls[3];
    q = lq[0] + lq[1] + lq[2] + lq[3];
    float mu  = s * (1.f / NDIM);
    float var = q * (1.f / NDIM) - mu * mu;
    float rs  = rsqrtf(var + LN_EPS);
    float4 g0 = ((const float4*)g)[tid], g1 = ((const float4*)g)[tid + 256];
    float4 b0 = ((const float4*)b)[tid], b1 = ((const float4*)b)[tid + 256];
    float4 o0, o1;
    o0.x = (v0.x - mu) * rs * g0.x + b0.x;  o0.y = (v0.y - mu) * rs * g0.y + b0.y;
    o0.z = (v0.z - mu) * rs * g0.z + b0.z;  o0.w = (v0.w - mu) * rs * g0.w + b0.w;
    o1.x = (v1.x - mu) * rs * g1.x + b1.x;  o1.y = (v1.y - mu) * rs * g1.y + b1.y;
    o1.z = (v1.z - mu) * rs * g1.z + b1.z;  o1.w = (v1.w - mu) * rs * g1.w + b1.w;
    float4* op = (float4*)(out + (size_t)row * NDIM);
    op[tid] = o0; op[tid + 256] = o1;
}

// ---------------- attention: ONE WAVE per (head, 64-row chunk) ---------------
// No inter-wave coupling: K tile in registers (128 VGPR), q staged in LDS with
// conflict-free slice stride, V in registers issued right after QK^T, PV from
// registers + uniform LDS p broadcasts. 8 independent waves/CU.
__global__ __launch_bounds__(64, 2) void k_attn(const float* __restrict__ cacheK,
                                                const float* __restrict__ cacheV,
                                                const float* __restrict__ qws,
                                                const float* __restrict__ kws,
                                                const float* __restrict__ vws,
                                                float* __restrict__ part,   // [16h][129c][16m][128d]
                                                float* __restrict__ ms) {   // [16h][129c][16m][2]
    __shared__ float s_q[16 * 144];    // row stride 144, ds-slice stride 36 -> banks spread
    __shared__ float s_p[16][68];      // scores [m][t], row pad 68
    int bid = blockIdx.x;
    int h = bid / NCH, c = bid % NCH;
    int nT = (c < NCH - 1) ? TC : M_TOK;
    const float* Kb = (c < NCH - 1) ? cacheK + ((size_t)h * MAXLEN + (size_t)c * TC) * DHEAD
                                    : kws + (size_t)h * M_TOK * DHEAD;
    const float* Vb = (c < NCH - 1) ? cacheV + ((size_t)h * MAXLEN + (size_t)c * TC) * DHEAD
                                    : vws + (size_t)h * M_TOK * DHEAD;
    int lane = threadIdx.x;
    int tloc = lane & 15, ds = lane >> 4;

    // ---- stage q (issued first so its vmcnt wait doesn't drain K) ----
    {
        const float4* qp = (const float4*)(qws + (size_t)h * M_TOK * DHEAD);
        #pragma unroll
        for (int i = 0; i < 8; ++i) {
            int g = i * 64 + lane;            // float4 index in [0,512)
            float4 v = qp[g];
            int row = g >> 5, col4 = g & 31;  // col4 in [0,32)
            int sl = col4 >> 3, ii = col4 & 7;
            *(float4*)&s_q[row * 144 + sl * 36 + ii * 4] = v;
        }
    }

    // ---- issue K tile: 64 rows x 128 d in registers ----
    float4 kreg[4][8];
    #pragma unroll
    for (int r = 0; r < 4; ++r) {
        if (r * 16 < nT) {
            const float4* kp = (const float4*)(Kb + (size_t)(r * 16 + tloc) * DHEAD + ds * 32);
            #pragma unroll
            for (int i = 0; i < 8; ++i) kreg[r][i] = kp[i];
        }
    }
    __syncthreads();

    // ---- QK^T: 16 m x 64 t ----
    #pragma unroll 2
    for (int m = 0; m < 16; ++m) {
        float4 qf[8];
        const float* qrow = s_q + m * 144 + ds * 36;
        #pragma unroll
        for (int i = 0; i < 8; ++i) qf[i] = *(const float4*)(qrow + i * 4);
        #pragma unroll
        for (int r = 0; r < 4; ++r) {
            if (r * 16 < nT) {
                float a0 = 0.f, a1 = 0.f, a2 = 0.f, a3 = 0.f;
                #pragma unroll
                for (int i = 0; i < 8; ++i) {
                    a0 = fmaf(kreg[r][i].x, qf[i].x, a0);
                    a1 = fmaf(kreg[r][i].y, qf[i].y, a1);
                    a2 = fmaf(kreg[r][i].z, qf[i].z, a2);
                    a3 = fmaf(kreg[r][i].w, qf[i].w, a3);
                }
                float s0 = (a0 + a1) + (a2 + a3);
                s0 += __shfl_xor(s0, 16);
                s0 += __shfl_xor(s0, 32);
                if (ds == 0) s_p[m][r * 16 + tloc] = s0 * RSQRT_D;
            }
        }
    }

    // ---- issue V tile: 64 rows, lane owns d-pair 2*lane (latency hides under softmax)
    float2 vv[64];
    #pragma unroll
    for (int i = 0; i < 64; ++i) {
        int t = (i < nT) ? i : 0;
        vv[i] = *(const float2*)(Vb + (size_t)t * DHEAD + 2 * lane);
    }
    __syncthreads();

    // ---- softmax: lane (m = lane&15, q16 = lane>>4) owns 16 t ----
    {
        int sm_m = lane & 15, q16 = lane >> 4;
        bool valid = (q16 * 16) < nT;
        float4 P[4];
        float mx = -1e30f;
        if (valid) {
            #pragma unroll
            for (int j = 0; j < 4; ++j) {
                P[j] = *(const float4*)&s_p[sm_m][q16 * 16 + j * 4];
                mx = fmaxf(mx, fmaxf(fmaxf(P[j].x, P[j].y), fmaxf(P[j].z, P[j].w)));
            }
        }
        mx = fmaxf(mx, __shfl_xor(mx, 16));
        mx = fmaxf(mx, __shfl_xor(mx, 32));
        float smv = 0.f;
        #pragma unroll
        for (int j = 0; j < 4; ++j) {
            if (valid) {
                P[j].x = __expf(P[j].x - mx); P[j].y = __expf(P[j].y - mx);
                P[j].z = __expf(P[j].z - mx); P[j].w = __expf(P[j].w - mx);
                smv += (P[j].x + P[j].y) + (P[j].z + P[j].w);
            } else {
                P[j].x = P[j].y = P[j].z = P[j].w = 0.f;
            }
            *(float4*)&s_p[sm_m][q16 * 16 + j * 4] = P[j];
        }
        smv += __shfl_xor(smv, 16);
        smv += __shfl_xor(smv, 32);
        if (lane < 16) {
            float* msp = ms + ((size_t)(h * NCH + c) * 16 + sm_m) * 2;
            msp[0] = mx; msp[1] = smv;
        }
    }
    __syncthreads();

    // ---- PV: full chunk per wave, V in regs, p via uniform LDS broadcast ----
    float2 acc[16];
    #pragma unroll
    for (int i = 0; i < 16; ++i) { acc[i].x = 0.f; acc[i].y = 0.f; }
    #pragma unroll
    for (int tt = 0; tt < 8; ++tt) {
        #pragma unroll
        for (int m = 0; m < 16; ++m) {
            float4 p0 = *(const float4*)&s_p[m][tt * 8];
            float4 p1 = *(const float4*)&s_p[m][tt * 8 + 4];
            acc[m].x = fmaf(p0.x, vv[tt*8+0].x, acc[m].x);
            acc[m].y = fmaf(p0.x, vv[tt*8+0].y, acc[m].y);
            acc[m].x = fmaf(p0.y, vv[tt*8+1].x, acc[m].x);
            acc[m].y = fmaf(p0.y, vv[tt*8+1].y, acc[m].y);
            acc[m].x = fmaf(p0.z, vv[tt*8+2].x, acc[m].x);
            acc[m].y = fmaf(p0.z, vv[tt*8+2].y, acc[m].y);
            acc[m].x = fmaf(p0.w, vv[tt*8+3].x, acc[m].x);
            acc[m].y = fmaf(p0.w, vv[tt*8+3].y, acc[m].y);
            acc[m].x = fmaf(p1.x, vv[tt*8+4].x, acc[m].x);
            acc[m].y = fmaf(p1.x, vv[tt*8+4].y, acc[m].y);
            acc[m].x = fmaf(p1.y, vv[tt*8+5].x, acc[m].x);
            acc[m].y = fmaf(p1.y, vv[tt*8+5].y, acc[m].y);
            acc[m].x = fmaf(p1.z, vv[tt*8+6].x, acc[m].x);
            acc[m].y = fmaf(p1.z, vv[tt*8+6].y, acc[m].y);
            acc[m].x = fmaf(p1.w, vv[tt*8+7].x, acc[m].x);
            acc[m].y = fmaf(p1.w, vv[tt*8+7].y, acc[m].y);
        }
    }
    float* dp = part + ((size_t)(h * NCH + c) * 16) * DHEAD + 2 * lane;
    #pragma unroll
    for (int m = 0; m < 16; ++m)
        *(float2*)(dp + (size_t)m * DHEAD) = acc[m];
}

// ---------------- combine chunk partials: block per (head, 16-d slice) -------
__global__ __launch_bounds__(256) void k_combine(const float* __restrict__ part,
                                                 const float* __restrict__ ms,
                                                 float* __restrict__ attnout) {
    __shared__ float s_scale[16][NCH + 3];
    int h = blockIdx.x >> 3, dblk = blockIdx.x & 7;
    int tid = threadIdx.x;
    {
        int cl = tid & 15, m = tid >> 4;    // 16 c-lanes per m, contiguous in wave
        float gmax = -1e30f;
        for (int c = cl; c < NCH; c += 16)
            gmax = fmaxf(gmax, ms[((size_t)(h * NCH + c) * 16 + m) * 2]);
        #pragma unroll
        for (int o = 8; o; o >>= 1) gmax = fmaxf(gmax, __shfl_xor(gmax, o));
        float denom = 0.f;
        for (int c = cl; c < NCH; c += 16) {
            const float* msp = ms + ((size_t)(h * NCH + c) * 16 + m) * 2;
            denom += msp[1] * __expf(msp[0] - gmax);
        }
        #pragma unroll
        for (int o = 8; o; o >>= 1) denom += __shfl_xor(denom, o);
        float inv = 1.f / denom;
        for (int c = cl; c < NCH; c += 16) {
            const float* msp = ms + ((size_t)(h * NCH + c) * 16 + m) * 2;
            s_scale[m][c] = __expf(msp[0] - gmax) * inv;
        }
    }
    __syncthreads();
    int m = tid >> 4, dd = tid & 15;
    int d = dblk * 16 + dd;
    const float* pp = part + ((size_t)h * NCH * 16 + m) * DHEAD + d;
    float acc = 0.f;
    #pragma unroll 4
    for (int c = 0; c < NCH; ++c)
        acc = fmaf(pp[(size_t)c * 16 * DHEAD], s_scale[m][c], acc);
    attnout[(size_t)m * NDIM + h * DHEAD + d] = acc;
}

// ---------------- launcher ----------------
extern "C" void kernel_launch(void* const* d_in, const int* in_sizes, int n_in,
                              void* d_out, int out_size, void* d_ws, size_t ws_size,
                              hipStream_t stream) {
    const float* X      = (const float*)d_in[0];
    const float* ln1_g  = (const float*)d_in[1];
    const float* ln1_b  = (const float*)d_in[2];
    const float* Wq     = (const float*)d_in[3];
    const float* Wk     = (const float*)d_in[4];
    const float* Wv     = (const float*)d_in[5];
    const float* Wo     = (const float*)d_in[6];
    const float* ln2_g  = (const float*)d_in[7];
    const float* ln2_b  = (const float*)d_in[8];
    const float* Wup    = (const float*)d_in[9];
    const float* Wdown  = (const float*)d_in[10];
    const float* cacheK = (const float*)d_in[11];
    const float* cacheV = (const float*)d_in[12];
    float* out = (float*)d_out;

    float* ws = (float*)d_ws;
    float* Xn1    = ws;                       // 32768
    float* qws    = Xn1 + 32768;              // 32768
    float* kws    = qws + 32768;              // 32768
    float* vws    = kws + 32768;              // 32768
    float* partb  = vws + 32768;              // 16*129*16*128 = 4227072
    float* msb    = partb + 4227072;          // 16*129*16*2   = 66048
    float* attn_o = msb + 66048;              // 32768
    float* X2     = attn_o + 32768;           // 32768
    float* Xn2    = X2 + 32768;               // 32768
    float* ffnh   = Xn2 + 32768;              // 131072

    k_ln<<<M_TOK, 256, 0, stream>>>(X, ln1_g, ln1_b, Xn1);
    k_qkv<<<1536, 256, 0, stream>>>(Xn1, Wq, Wk, Wv, qws, kws, vws);
    k_attn<<<NHEAD * NCH, 64, 0, stream>>>(cacheK, cacheV, qws, kws, vws, partb, msb);
    k_combine<<<NHEAD * 8, 256, 0, stream>>>(partb, msb, attn_o);
    k_resid<2048><<<1024, 256, 0, stream>>>(attn_o, Wo, X, X2);
    k_ln<<<M_TOK, 256, 0, stream>>>(X2, ln2_g, ln2_b, Xn2);
    k_up<<<2048, 256, 0, stream>>>(Xn2, Wup, ffnh);
    k_resid<8192><<<1024, 256, 0, stream>>>(ffnh, Wdown, X2, out);
}

// Round 8
// 155.579 us; speedup vs baseline: 1.2518x; 1.1561x over previous
//
#include <hip/hip_runtime.h>
#include <hip/hip_bf16.h>
#include <math.h>

#define M_TOK 16
#define NDIM  2048
#define DHEAD 128
#define NHEAD 16
#define MAXLEN 8448
#define FFN   8192
#define TC    128
#define NCH   65   // 64 cache chunks of 128 + 1 chunk of the 16 new rows
#define LN_EPS 1e-5f
#define RSQRT_D 0.08838834764831845f  // 1/sqrt(128)

#define AS1 __attribute__((address_space(1)))
#define AS3 __attribute__((address_space(3)))

// async global->LDS DMA: lane i writes 16B at lds_base + i*16 (wave-uniform base)
__device__ __forceinline__ void gload_lds16(const float* g, float* l) {
    __builtin_amdgcn_global_load_lds((AS1 void*)g, (AS3 void*)l, 16, 0, 0);
}

// ================= fold reduce =================
template<int H>
__device__ __forceinline__ void fold_step(float* v, int lane, int o) {
    bool hi = (lane & o) != 0;
    #pragma unroll
    for (int i = 0; i < H; ++i) {
        float send = hi ? v[i] : v[i + H];
        float keep = hi ? v[i + H] : v[i];
        v[i] = keep + __shfl_xor(send, o);
    }
}

__device__ __forceinline__ void fold64(float* v, int lane) {
    fold_step<32>(v, lane, 32);
    fold_step<16>(v, lane, 16);
    fold_step<8>(v, lane, 8);
    fold_step<4>(v, lane, 4);
    fold_step<2>(v, lane, 2);
    fold_step<1>(v, lane, 1);
}

// ================= split-K GEMV core (R3 form) =================
template<int KDIM>
__device__ __forceinline__ void gemv_splitk(const float* __restrict__ A,
                                            const float* __restrict__ W,
                                            int col0, int wid, int lane,
                                            float* v) {
    const int kbase = wid * (KDIM / 4);
    const float* wp = W + (size_t)col0 * KDIM + kbase + lane * 4;
    const float* ap = A + kbase + lane * 4;
    #pragma unroll 1
    for (int kc = 0; kc < KDIM / 4; kc += 256) {
        float4 w4[4];
        #pragma unroll
        for (int c = 0; c < 4; ++c)
            w4[c] = *(const float4*)(wp + (size_t)c * KDIM + kc);
        #pragma unroll
        for (int m = 0; m < 16; ++m) {
            float4 x4 = *(const float4*)(ap + (size_t)m * KDIM + kc);
            #pragma unroll
            for (int c = 0; c < 4; ++c) {
                v[m * 4 + c] = fmaf(w4[c].x, x4.x, v[m * 4 + c]);
                v[m * 4 + c] = fmaf(w4[c].y, x4.y, v[m * 4 + c]);
                v[m * 4 + c] = fmaf(w4[c].z, x4.z, v[m * 4 + c]);
                v[m * 4 + c] = fmaf(w4[c].w, x4.w, v[m * 4 + c]);
            }
        }
    }
}

__device__ __forceinline__ float crosswave_reduce(float val, int wid, int lane,
                                                  float (*s_red)[64]) {
    if (wid != 0) s_red[wid - 1][lane] = val;
    __syncthreads();
    return val + s_red[0][lane] + s_red[1][lane] + s_red[2][lane];
}

// ---------------- fused QKV GEMV ----------------
__global__ __launch_bounds__(256) void k_qkv(const float* __restrict__ Xn,
                                             const float* __restrict__ Wq,
                                             const float* __restrict__ Wk,
                                             const float* __restrict__ Wv,
                                             float* __restrict__ qws,
                                             float* __restrict__ kws,
                                             float* __restrict__ vws) {
    __shared__ float s_red[3][64];
    int tid = threadIdx.x, wid = tid >> 6, lane = tid & 63;
    int b = blockIdx.x;
    int sel = b >> 9;
    int cb = (b & 511) * 4;
    const float* W = (sel == 0) ? Wq : (sel == 1) ? Wk : Wv;
    float* dst = (sel == 0) ? qws : (sel == 1) ? kws : vws;
    float v[64];
    #pragma unroll
    for (int i = 0; i < 64; ++i) v[i] = 0.f;
    gemv_splitk<2048>(Xn, W, cb, wid, lane, v);
    fold64(v, lane);
    float r = crosswave_reduce(v[0], wid, lane, s_red);
    if (wid == 0) {
        int m = lane >> 2, c = lane & 3;
        int gcol = cb + c;
        int h = gcol >> 7, d = gcol & 127;
        dst[(((size_t)h * 16 + m) << 7) + d] = r;
    }
}

// ---------------- Wup GEMV + gelu ----------------
__device__ __forceinline__ float gelu_exact(float x) {
    return 0.5f * x * (1.0f + erff(x * 0.7071067811865475f));
}

__global__ __launch_bounds__(256) void k_up(const float* __restrict__ A,
                                            const float* __restrict__ W,
                                            float* __restrict__ out) {
    __shared__ float s_red[3][64];
    int tid = threadIdx.x, wid = tid >> 6, lane = tid & 63;
    int cb = blockIdx.x * 4;
    float v[64];
    #pragma unroll
    for (int i = 0; i < 64; ++i) v[i] = 0.f;
    gemv_splitk<2048>(A, W, cb, wid, lane, v);
    fold64(v, lane);
    float r = crosswave_reduce(v[0], wid, lane, s_red);
    if (wid == 0) {
        int m = lane >> 2, c = lane & 3;
        out[(size_t)m * FFN + cb + c] = gelu_exact(r);
    }
}

// ---------------- GEMV + residual (R3 form, 4 cols/block) ----------------
template<int KDIM>
__global__ __launch_bounds__(256) void k_resid(const float* __restrict__ A,
                                               const float* __restrict__ W,
                                               const float* __restrict__ R,
                                               float* __restrict__ out) {
    __shared__ float s_red[3][64];
    int tid = threadIdx.x, wid = tid >> 6, lane = tid & 63;
    int cb = blockIdx.x * 4;               // 512 blocks
    float v[64];
    #pragma unroll
    for (int i = 0; i < 64; ++i) v[i] = 0.f;
    gemv_splitk<KDIM>(A, W, cb, wid, lane, v);
    fold64(v, lane);
    float r = crosswave_reduce(v[0], wid, lane, s_red);
    if (wid == 0) {
        int m = lane >> 2, c = lane & 3;
        int col = cb + c;
        out[(size_t)m * NDIM + col] = R[(size_t)m * NDIM + col] + r;
    }
}

// ---------------- LayerNorm: one block per row ----------------
__global__ __launch_bounds__(256) void k_ln(const float* __restrict__ X,
                                            const float* __restrict__ g,
                                            const float* __restrict__ b,
                                            float* __restrict__ out) {
    int row = blockIdx.x, tid = threadIdx.x;
    const float4* xp = (const float4*)(X + (size_t)row * NDIM);
    float4 v0 = xp[tid], v1 = xp[tid + 256];
    float s = v0.x + v0.y + v0.z + v0.w + v1.x + v1.y + v1.z + v1.w;
    float q = v0.x*v0.x + v0.y*v0.y + v0.z*v0.z + v0.w*v0.w
            + v1.x*v1.x + v1.y*v1.y + v1.z*v1.z + v1.w*v1.w;
    #pragma unroll
    for (int o = 32; o; o >>= 1) { s += __shfl_xor(s, o); q += __shfl_xor(q, o); }
    __shared__ float ls[4], lq[4];
    int wid = tid >> 6, lane = tid & 63;
    if (lane == 0) { ls[wid] = s; lq[wid] = q; }
    __syncthreads();
    s = ls[0] + ls[1] + ls[2] + ls[3];
    q = lq[0] + lq[1] + lq[2] + lq[3];
    float mu  = s * (1.f / NDIM);
    float var = q * (1.f / NDIM) - mu * mu;
    float rs  = rsqrtf(var + LN_EPS);
    float4 g0 = ((const float4*)g)[tid], g1 = ((const float4*)g)[tid + 256];
    float4 b0 = ((const float4*)b)[tid], b1 = ((const float4*)b)[tid + 256];
    float4 o0, o1;
    o0.x = (v0.x - mu) * rs * g0.x + b0.x;  o0.y = (v0.y - mu) * rs * g0.y + b0.y;
    o0.z = (v0.z - mu) * rs * g0.z + b0.z;  o0.w = (v0.w - mu) * rs * g0.w + b0.w;
    o1.x = (v1.x - mu) * rs * g1.x + b1.x;  o1.y = (v1.y - mu) * rs * g1.y + b1.y;
    o1.z = (v1.z - mu) * rs * g1.z + b1.z;  o1.w = (v1.w - mu) * rs * g1.w + b1.w;
    float4* op = (float4*)(out + (size_t)row * NDIM);
    op[tid] = o0; op[tid + 256] = o1;
}

// ---------------- attention: DMA-pipelined, counted vmcnt ----------------
// Block = (head, 128-row chunk), 4 waves. K/V stream through double-buffered
// LDS via global_load_lds; per wave 2 loads/slot, waits are s_waitcnt vmcnt(2)
// (never 0 mid-loop) so DMA stays in flight across barriers. Each 1KB DMA
// segment (2 rows) is placed at a 1040B-stride slot -> row reads spread banks.
__global__ __launch_bounds__(256) void k_attn(const float* __restrict__ cacheK,
                                              const float* __restrict__ cacheV,
                                              const float* __restrict__ qws,
                                              const float* __restrict__ kws,
                                              const float* __restrict__ vws,
                                              float* __restrict__ part,   // [16h][65c][16m][128d]
                                              float* __restrict__ ms) {   // [16h][65c][16m][2]
    __shared__ float s_k[2][2080];   // 16-row tile: pair j (2 rows) at float 260*j
    __shared__ float s_v[2][2080];
    __shared__ float s_q[16 * 144];  // row m at 144*m, 32-float slice ds at +36*ds
    __shared__ float s_p[16][132];   // scores [m][t]
    int bid = blockIdx.x;
    int h = bid / NCH, c = bid % NCH;
    int nT = (c < NCH - 1) ? TC : M_TOK;
    int NST = nT >> 4;               // 8 full subtiles, or 1 for the tail chunk
    const float* Kb = (c < NCH - 1) ? cacheK + ((size_t)h * MAXLEN + (size_t)c * TC) * DHEAD
                                    : kws + (size_t)h * M_TOK * DHEAD;
    const float* Vb = (c < NCH - 1) ? cacheV + ((size_t)h * MAXLEN + (size_t)c * TC) * DHEAD
                                    : vws + (size_t)h * M_TOK * DHEAD;
    int tid = threadIdx.x, w = tid >> 6, lane = tid & 63;
    int tloc = lane & 15, ds = lane >> 4;

    // stage q (normal loads; their vmcnt drains before any DMA is issued)
    {
        const float4* qp = (const float4*)(qws + (size_t)h * M_TOK * DHEAD);
        #pragma unroll
        for (int i = 0; i < 2; ++i) {
            int g = i * 256 + tid;           // float4 idx in [0,512)
            float4 v = qp[g];
            int row = g >> 5, col4 = g & 31;
            *(float4*)&s_q[row * 144 + (col4 >> 3) * 36 + (col4 & 7) * 4] = v;
        }
    }

    // slot [0,NST) = K tile, [NST,2NST) = V tile; wave stages pairs 2w, 2w+1
    auto issue = [&](int slot) {
        if (slot >= 2 * NST) return;
        const float* src; float* dst;
        if (slot < NST) { src = Kb + (size_t)slot * 16 * DHEAD; dst = s_k[slot & 1]; }
        else { int j = slot - NST; src = Vb + (size_t)j * 16 * DHEAD; dst = s_v[j & 1]; }
        #pragma unroll
        for (int k = 0; k < 2; ++k) {
            int j = w * 2 + k;
            gload_lds16(src + j * 256 + lane * 4, dst + j * 260);
        }
    };

    issue(0);
    issue(1);
    const int lastSlot = 2 * NST - 1;

    // ================= K steps: QK^T =================
    for (int s = 0; s < NST; ++s) {
        if (s == lastSlot) asm volatile("s_waitcnt vmcnt(0) lgkmcnt(0)" ::: "memory");
        else               asm volatile("s_waitcnt vmcnt(2) lgkmcnt(0)" ::: "memory");
        __builtin_amdgcn_s_barrier();
        const float* kbase = s_k[s & 1] + (tloc >> 1) * 260 + (tloc & 1) * 128 + ds * 32;
        float4 kr[8];
        #pragma unroll
        for (int i = 0; i < 8; ++i) kr[i] = *(const float4*)(kbase + i * 4);
        asm volatile("s_waitcnt lgkmcnt(0)" ::: "memory");
        __builtin_amdgcn_s_barrier();
        issue(s + 2);
        #pragma unroll
        for (int mm = 0; mm < 4; ++mm) {
            int m = w * 4 + mm;
            const float* qrow = s_q + m * 144 + ds * 36;
            float a0 = 0.f, a1 = 0.f, a2 = 0.f, a3 = 0.f;
            #pragma unroll
            for (int i = 0; i < 8; ++i) {
                float4 q4 = *(const float4*)(qrow + i * 4);
                a0 = fmaf(kr[i].x, q4.x, a0); a1 = fmaf(kr[i].y, q4.y, a1);
                a2 = fmaf(kr[i].z, q4.z, a2); a3 = fmaf(kr[i].w, q4.w, a3);
            }
            float s0 = (a0 + a1) + (a2 + a3);
            s0 += __shfl_xor(s0, 16);
            s0 += __shfl_xor(s0, 32);
            if (ds == 0) s_p[m][s * 16 + tloc] = s0 * RSQRT_D;
        }
    }

    // ================= softmax =================
    asm volatile("s_waitcnt lgkmcnt(0)" ::: "memory");
    __builtin_amdgcn_s_barrier();
    {
        int m2 = tid >> 4, tl = tid & 15;
        float mx = -1e30f;
        for (int t = tl; t < nT; t += 16) mx = fmaxf(mx, s_p[m2][t]);
        #pragma unroll
        for (int o = 8; o; o >>= 1) mx = fmaxf(mx, __shfl_xor(mx, o));
        float sm = 0.f;
        for (int t = tl; t < nT; t += 16) {
            float p = __expf(s_p[m2][t] - mx);
            s_p[m2][t] = p;
            sm += p;
        }
        #pragma unroll
        for (int o = 8; o; o >>= 1) sm += __shfl_xor(sm, o);
        if (tl == 0) {
            float* msp = ms + ((size_t)(h * NCH + c) * 16 + m2) * 2;
            msp[0] = mx; msp[1] = sm;
        }
    }
    // PV's first (vmcnt+barrier) also publishes the softmax writes

    // ================= V steps: PV =================
    float2 acc[4] = {{0.f,0.f},{0.f,0.f},{0.f,0.f},{0.f,0.f}};
    for (int j = 0; j < NST; ++j) {
        int s = NST + j;
        if (s == lastSlot) asm volatile("s_waitcnt vmcnt(0) lgkmcnt(0)" ::: "memory");
        else               asm volatile("s_waitcnt vmcnt(2) lgkmcnt(0)" ::: "memory");
        __builtin_amdgcn_s_barrier();
        float2 vr[16];
        const float* vbase = s_v[j & 1];
        #pragma unroll
        for (int r = 0; r < 16; ++r)
            vr[r] = *(const float2*)(vbase + (r >> 1) * 260 + (r & 1) * 128 + lane * 2);
        asm volatile("s_waitcnt lgkmcnt(0)" ::: "memory");
        __builtin_amdgcn_s_barrier();
        issue(s + 2);
        #pragma unroll
        for (int mm = 0; mm < 4; ++mm) {
            int m = w * 4 + mm;
            const float* prow = &s_p[m][j * 16];
            #pragma unroll
            for (int g4 = 0; g4 < 4; ++g4) {
                float4 p4 = *(const float4*)(prow + g4 * 4);
                acc[mm].x = fmaf(p4.x, vr[g4*4+0].x, acc[mm].x);
                acc[mm].y = fmaf(p4.x, vr[g4*4+0].y, acc[mm].y);
                acc[mm].x = fmaf(p4.y, vr[g4*4+1].x, acc[mm].x);
                acc[mm].y = fmaf(p4.y, vr[g4*4+1].y, acc[mm].y);
                acc[mm].x = fmaf(p4.z, vr[g4*4+2].x, acc[mm].x);
                acc[mm].y = fmaf(p4.z, vr[g4*4+2].y, acc[mm].y);
                acc[mm].x = fmaf(p4.w, vr[g4*4+3].x, acc[mm].x);
                acc[mm].y = fmaf(p4.w, vr[g4*4+3].y, acc[mm].y);
            }
        }
    }

    float* dp = part + (((size_t)(h * NCH + c) * 16) + w * 4) * DHEAD + 2 * lane;
    #pragma unroll
    for (int mm = 0; mm < 4; ++mm)
        *(float2*)(dp + (size_t)mm * DHEAD) = acc[mm];
}

// ---------------- combine chunk partials: block per (head, 16-d slice) -------
__global__ __launch_bounds__(256) void k_combine(const float* __restrict__ part,
                                                 const float* __restrict__ ms,
                                                 float* __restrict__ attnout) {
    __shared__ float s_scale[16][NCH + 3];
    int h = blockIdx.x >> 3, dblk = blockIdx.x & 7;
    int tid = threadIdx.x;
    {
        int cl = tid & 15, m = tid >> 4;
        float gmax = -1e30f;
        for (int c = cl; c < NCH; c += 16)
            gmax = fmaxf(gmax, ms[((size_t)(h * NCH + c) * 16 + m) * 2]);
        #pragma unroll
        for (int o = 8; o; o >>= 1) gmax = fmaxf(gmax, __shfl_xor(gmax, o));
        float denom = 0.f;
        for (int c = cl; c < NCH; c += 16) {
            const float* msp = ms + ((size_t)(h * NCH + c) * 16 + m) * 2;
            denom += msp[1] * __expf(msp[0] - gmax);
        }
        #pragma unroll
        for (int o = 8; o; o >>= 1) denom += __shfl_xor(denom, o);
        float inv = 1.f / denom;
        for (int c = cl; c < NCH; c += 16) {
            const float* msp = ms + ((size_t)(h * NCH + c) * 16 + m) * 2;
            s_scale[m][c] = __expf(msp[0] - gmax) * inv;
        }
    }
    __syncthreads();
    int m = tid >> 4, dd = tid & 15;
    int d = dblk * 16 + dd;
    const float* pp = part + ((size_t)h * NCH * 16 + m) * DHEAD + d;
    float acc = 0.f;
    #pragma unroll 4
    for (int c = 0; c < NCH; ++c)
        acc = fmaf(pp[(size_t)c * 16 * DHEAD], s_scale[m][c], acc);
    attnout[(size_t)m * NDIM + h * DHEAD + d] = acc;
}

// ---------------- launcher ----------------
extern "C" void kernel_launch(void* const* d_in, const int* in_sizes, int n_in,
                              void* d_out, int out_size, void* d_ws, size_t ws_size,
                              hipStream_t stream) {
    const float* X      = (const float*)d_in[0];
    const float* ln1_g  = (const float*)d_in[1];
    const float* ln1_b  = (const float*)d_in[2];
    const float* Wq     = (const float*)d_in[3];
    const float* Wk     = (const float*)d_in[4];
    const float* Wv     = (const float*)d_in[5];
    const float* Wo     = (const float*)d_in[6];
    const float* ln2_g  = (const float*)d_in[7];
    const float* ln2_b  = (const float*)d_in[8];
    const float* Wup    = (const float*)d_in[9];
    const float* Wdown  = (const float*)d_in[10];
    const float* cacheK = (const float*)d_in[11];
    const float* cacheV = (const float*)d_in[12];
    float* out = (float*)d_out;

    float* ws = (float*)d_ws;
    float* Xn1    = ws;                       // 32768
    float* qws    = Xn1 + 32768;              // 32768
    float* kws    = qws + 32768;              // 32768
    float* vws    = kws + 32768;              // 32768
    float* partb  = vws + 32768;              // 16*65*16*128 = 2129920
    float* msb    = partb + 2129920;          // 16*65*16*2   = 33280
    float* attn_o = msb + 33280;              // 32768
    float* X2     = attn_o + 32768;           // 32768
    float* Xn2    = X2 + 32768;               // 32768
    float* ffnh   = Xn2 + 32768;              // 131072

    k_ln<<<M_TOK, 256, 0, stream>>>(X, ln1_g, ln1_b, Xn1);
    k_qkv<<<1536, 256, 0, stream>>>(Xn1, Wq, Wk, Wv, qws, kws, vws);
    k_attn<<<NHEAD * NCH, 256, 0, stream>>>(cacheK, cacheV, qws, kws, vws, partb, msb);
    k_combine<<<NHEAD * 8, 256, 0, stream>>>(partb, msb, attn_o);
    k_resid<2048><<<512, 256, 0, stream>>>(attn_o, Wo, X, X2);
    k_ln<<<M_TOK, 256, 0, stream>>>(X2, ln2_g, ln2_b, Xn2);
    k_up<<<2048, 256, 0, stream>>>(Xn2, Wup, ffnh);
    k_resid<8192><<<512, 256, 0, stream>>>(ffnh, Wdown, X2, out);
}

// Round 9
// 144.589 us; speedup vs baseline: 1.3470x; 1.0760x over previous
//
#include <hip/hip_runtime.h>
#include <hip/hip_bf16.h>
#include <math.h>

#define M_TOK 16
#define NDIM  2048
#define DHEAD 128
#define NHEAD 16
#define MAXLEN 8448
#define FFN   8192
#define TC    128
#define NCH   65   // 64 cache chunks of 128 + 1 chunk of the 16 new rows
#define LN_EPS 1e-5f
#define RSQRT_D 0.08838834764831845f  // 1/sqrt(128)

#define AS1 __attribute__((address_space(1)))
#define AS3 __attribute__((address_space(3)))

// async global->LDS DMA: lane i writes 16B at lds_base + i*16 (wave-uniform base)
__device__ __forceinline__ void gload_lds16(const float* g, float* l) {
    __builtin_amdgcn_global_load_lds((AS1 void*)g, (AS3 void*)l, 16, 0, 0);
}

// ================= fold reduce =================
template<int H>
__device__ __forceinline__ void fold_step(float* v, int lane, int o) {
    bool hi = (lane & o) != 0;
    #pragma unroll
    for (int i = 0; i < H; ++i) {
        float send = hi ? v[i] : v[i + H];
        float keep = hi ? v[i + H] : v[i];
        v[i] = keep + __shfl_xor(send, o);
    }
}

// 16 partials per lane -> lane L holds full 64-lane sum of value (L>>2)
__device__ __forceinline__ void fold16(float* v, int lane) {
    fold_step<8>(v, lane, 32);
    fold_step<4>(v, lane, 16);
    fold_step<2>(v, lane, 8);
    fold_step<1>(v, lane, 4);
    v[0] += __shfl_xor(v[0], 2);
    v[0] += __shfl_xor(v[0], 1);
}

// ================= GEMV core: DMA-pipelined, counted vmcnt ===================
// Block = 4 cols x 16 m. 4 waves split m (wave w -> m = 4w..4w+3); every wave
// computes all 4 cols. Per 256-k slot, W (4x256) and x (16x256) are staged to
// LDS via global_load_lds: 5 segs per wave per slot, s_waitcnt vmcnt(5) keeps
// the next slot's 5 segs in flight across barriers (never drain mid-loop).
// Inner loop touches only LDS + FMA. No cross-wave reduction needed.
template<int KDIM>
__device__ __forceinline__ void gemv_core16(const float* __restrict__ A,
                                            const float* __restrict__ W,
                                            int cb, int w, int lane,
                                            float* sbuf, float* acc) {
    constexpr int NS = KDIM / 256;
    const float* wsrc = W + (size_t)(cb + w) * KDIM + lane * 4;
    auto issue = [&](int s) {
        if (s >= NS) return;
        float* dst = sbuf + (s & 1) * 5120;
        gload_lds16(wsrc + s * 256, dst + w * 256);
        #pragma unroll
        for (int j = 0; j < 4; ++j) {
            int m = w * 4 + j;
            gload_lds16(A + (size_t)m * KDIM + s * 256 + lane * 4,
                        dst + 1024 + m * 256);
        }
    };
    issue(0);
    issue(1);
    #pragma unroll 1
    for (int s = 0; s < NS; ++s) {
        if (s == NS - 1) asm volatile("s_waitcnt vmcnt(0) lgkmcnt(0)" ::: "memory");
        else             asm volatile("s_waitcnt vmcnt(5) lgkmcnt(0)" ::: "memory");
        __builtin_amdgcn_s_barrier();
        const float* buf = sbuf + (s & 1) * 5120;
        float4 wr[4], xr[4];
        #pragma unroll
        for (int c = 0; c < 4; ++c)
            wr[c] = *(const float4*)(buf + c * 256 + lane * 4);
        #pragma unroll
        for (int j = 0; j < 4; ++j)
            xr[j] = *(const float4*)(buf + 1024 + (w * 4 + j) * 256 + lane * 4);
        asm volatile("s_waitcnt lgkmcnt(0)" ::: "memory");
        __builtin_amdgcn_s_barrier();
        issue(s + 2);
        #pragma unroll
        for (int j = 0; j < 4; ++j) {
            #pragma unroll
            for (int c = 0; c < 4; ++c) {
                acc[j*4+c] = fmaf(wr[c].x, xr[j].x, acc[j*4+c]);
                acc[j*4+c] = fmaf(wr[c].y, xr[j].y, acc[j*4+c]);
                acc[j*4+c] = fmaf(wr[c].z, xr[j].z, acc[j*4+c]);
                acc[j*4+c] = fmaf(wr[c].w, xr[j].w, acc[j*4+c]);
            }
        }
    }
}

// ---------------- fused QKV GEMV ----------------
__global__ __launch_bounds__(256) void k_qkv(const float* __restrict__ Xn,
                                             const float* __restrict__ Wq,
                                             const float* __restrict__ Wk,
                                             const float* __restrict__ Wv,
                                             float* __restrict__ qws,
                                             float* __restrict__ kws,
                                             float* __restrict__ vws) {
    __shared__ float sbuf[2 * 5120];
    int tid = threadIdx.x, w = tid >> 6, lane = tid & 63;
    int b = blockIdx.x;                    // 0..1535
    int sel = b >> 9;
    int cb = (b & 511) * 4;
    const float* W = (sel == 0) ? Wq : (sel == 1) ? Wk : Wv;
    float* dst = (sel == 0) ? qws : (sel == 1) ? kws : vws;
    float acc[16];
    #pragma unroll
    for (int i = 0; i < 16; ++i) acc[i] = 0.f;
    gemv_core16<2048>(Xn, W, cb, w, lane, sbuf, acc);
    fold16(acc, lane);
    if ((lane & 3) == 0) {
        int idx = lane >> 2;
        int j = idx >> 2, c = idx & 3;
        int m = w * 4 + j;
        int gcol = cb + c;
        int hh = gcol >> 7, d = gcol & 127;
        dst[(((size_t)hh * 16 + m) << 7) + d] = acc[0];
    }
}

// ---------------- Wup GEMV + gelu ----------------
__device__ __forceinline__ float gelu_exact(float x) {
    return 0.5f * x * (1.0f + erff(x * 0.7071067811865475f));
}

__global__ __launch_bounds__(256) void k_up(const float* __restrict__ A,
                                            const float* __restrict__ W,
                                            float* __restrict__ out) {
    __shared__ float sbuf[2 * 5120];
    int tid = threadIdx.x, w = tid >> 6, lane = tid & 63;
    int cb = blockIdx.x * 4;               // 2048 blocks
    float acc[16];
    #pragma unroll
    for (int i = 0; i < 16; ++i) acc[i] = 0.f;
    gemv_core16<2048>(A, W, cb, w, lane, sbuf, acc);
    fold16(acc, lane);
    if ((lane & 3) == 0) {
        int idx = lane >> 2;
        int j = idx >> 2, c = idx & 3;
        int m = w * 4 + j;
        out[(size_t)m * FFN + cb + c] = gelu_exact(acc[0]);
    }
}

// ---------------- GEMV + residual ----------------
template<int KDIM>
__global__ __launch_bounds__(256) void k_resid(const float* __restrict__ A,
                                               const float* __restrict__ W,
                                               const float* __restrict__ R,
                                               float* __restrict__ out) {
    __shared__ float sbuf[2 * 5120];
    int tid = threadIdx.x, w = tid >> 6, lane = tid & 63;
    int cb = blockIdx.x * 4;               // 512 blocks
    float acc[16];
    #pragma unroll
    for (int i = 0; i < 16; ++i) acc[i] = 0.f;
    gemv_core16<KDIM>(A, W, cb, w, lane, sbuf, acc);
    fold16(acc, lane);
    if ((lane & 3) == 0) {
        int idx = lane >> 2;
        int j = idx >> 2, c = idx & 3;
        int m = w * 4 + j;
        int col = cb + c;
        out[(size_t)m * NDIM + col] = R[(size_t)m * NDIM + col] + acc[0];
    }
}

// ---------------- LayerNorm: one block per row ----------------
__global__ __launch_bounds__(256) void k_ln(const float* __restrict__ X,
                                            const float* __restrict__ g,
                                            const float* __restrict__ b,
                                            float* __restrict__ out) {
    int row = blockIdx.x, tid = threadIdx.x;
    const float4* xp = (const float4*)(X + (size_t)row * NDIM);
    float4 v0 = xp[tid], v1 = xp[tid + 256];
    float s = v0.x + v0.y + v0.z + v0.w + v1.x + v1.y + v1.z + v1.w;
    float q = v0.x*v0.x + v0.y*v0.y + v0.z*v0.z + v0.w*v0.w
            + v1.x*v1.x + v1.y*v1.y + v1.z*v1.z + v1.w*v1.w;
    #pragma unroll
    for (int o = 32; o; o >>= 1) { s += __shfl_xor(s, o); q += __shfl_xor(q, o); }
    __shared__ float ls[4], lq[4];
    int wid = tid >> 6, lane = tid & 63;
    if (lane == 0) { ls[wid] = s; lq[wid] = q; }
    __syncthreads();
    s = ls[0] + ls[1] + ls[2] + ls[3];
    q = lq[0] + lq[1] + lq[2] + lq[3];
    float mu  = s * (1.f / NDIM);
    float var = q * (1.f / NDIM) - mu * mu;
    float rs  = rsqrtf(var + LN_EPS);
    float4 g0 = ((const float4*)g)[tid], g1 = ((const float4*)g)[tid + 256];
    float4 b0 = ((const float4*)b)[tid], b1 = ((const float4*)b)[tid + 256];
    float4 o0, o1;
    o0.x = (v0.x - mu) * rs * g0.x + b0.x;  o0.y = (v0.y - mu) * rs * g0.y + b0.y;
    o0.z = (v0.z - mu) * rs * g0.z + b0.z;  o0.w = (v0.w - mu) * rs * g0.w + b0.w;
    o1.x = (v1.x - mu) * rs * g1.x + b1.x;  o1.y = (v1.y - mu) * rs * g1.y + b1.y;
    o1.z = (v1.z - mu) * rs * g1.z + b1.z;  o1.w = (v1.w - mu) * rs * g1.w + b1.w;
    float4* op = (float4*)(out + (size_t)row * NDIM);
    op[tid] = o0; op[tid + 256] = o1;
}

// ---------------- attention: DMA-pipelined, q in registers ----------------
// Block = (head, 128-row chunk), 4 waves. K/V stream through double-buffered
// LDS via global_load_lds with counted vmcnt(2). q is hoisted to VGPRs once
// (wave's 4 m-rows x lane's 32-float slice), cutting per-slot LDS issue from
// 40 b128 to 8 b128 per lane.
__global__ __launch_bounds__(256, 2) void k_attn(const float* __restrict__ cacheK,
                                                 const float* __restrict__ cacheV,
                                                 const float* __restrict__ qws,
                                                 const float* __restrict__ kws,
                                                 const float* __restrict__ vws,
                                                 float* __restrict__ part,   // [16h][65c][16m][128d]
                                                 float* __restrict__ ms) {   // [16h][65c][16m][2]
    __shared__ float s_k[2][2080];   // 16-row tile: pair j (2 rows) at float 260*j
    __shared__ float s_v[2][2080];
    __shared__ float s_p[16][132];   // scores [m][t]
    int bid = blockIdx.x;
    int h = bid / NCH, c = bid % NCH;
    int nT = (c < NCH - 1) ? TC : M_TOK;
    int NST = nT >> 4;               // 8 full subtiles, or 1 for the tail chunk
    const float* Kb = (c < NCH - 1) ? cacheK + ((size_t)h * MAXLEN + (size_t)c * TC) * DHEAD
                                    : kws + (size_t)h * M_TOK * DHEAD;
    const float* Vb = (c < NCH - 1) ? cacheV + ((size_t)h * MAXLEN + (size_t)c * TC) * DHEAD
                                    : vws + (size_t)h * M_TOK * DHEAD;
    int tid = threadIdx.x, w = tid >> 6, lane = tid & 63;
    int tloc = lane & 15, ds = lane >> 4;

    // hoist q into registers: wave's 4 m rows, lane's ds-slice (32 floats)
    float4 qreg[4][8];
    {
        const float4* qp = (const float4*)(qws + (size_t)h * M_TOK * DHEAD);
        #pragma unroll
        for (int mm = 0; mm < 4; ++mm) {
            #pragma unroll
            for (int i = 0; i < 8; ++i)
                qreg[mm][i] = qp[(size_t)(w * 4 + mm) * 32 + ds * 8 + i];
        }
    }
    // drain q loads BEFORE issuing DMA so no later wait drains the pipeline
    asm volatile("s_waitcnt vmcnt(0)" ::: "memory");

    // slot [0,NST) = K tile, [NST,2NST) = V tile; wave stages pairs 2w, 2w+1
    auto issue = [&](int slot) {
        if (slot >= 2 * NST) return;
        const float* src; float* dst;
        if (slot < NST) { src = Kb + (size_t)slot * 16 * DHEAD; dst = s_k[slot & 1]; }
        else { int j = slot - NST; src = Vb + (size_t)j * 16 * DHEAD; dst = s_v[j & 1]; }
        #pragma unroll
        for (int k = 0; k < 2; ++k) {
            int j = w * 2 + k;
            gload_lds16(src + j * 256 + lane * 4, dst + j * 260);
        }
    };

    issue(0);
    issue(1);
    const int lastSlot = 2 * NST - 1;

    // ================= K steps: QK^T =================
    for (int s = 0; s < NST; ++s) {
        if (s == lastSlot) asm volatile("s_waitcnt vmcnt(0) lgkmcnt(0)" ::: "memory");
        else               asm volatile("s_waitcnt vmcnt(2) lgkmcnt(0)" ::: "memory");
        __builtin_amdgcn_s_barrier();
        const float* kbase = s_k[s & 1] + (tloc >> 1) * 260 + (tloc & 1) * 128 + ds * 32;
        float4 kr[8];
        #pragma unroll
        for (int i = 0; i < 8; ++i) kr[i] = *(const float4*)(kbase + i * 4);
        asm volatile("s_waitcnt lgkmcnt(0)" ::: "memory");
        __builtin_amdgcn_s_barrier();
        issue(s + 2);
        #pragma unroll
        for (int mm = 0; mm < 4; ++mm) {
            float a0 = 0.f, a1 = 0.f, a2 = 0.f, a3 = 0.f;
            #pragma unroll
            for (int i = 0; i < 8; ++i) {
                a0 = fmaf(kr[i].x, qreg[mm][i].x, a0);
                a1 = fmaf(kr[i].y, qreg[mm][i].y, a1);
                a2 = fmaf(kr[i].z, qreg[mm][i].z, a2);
                a3 = fmaf(kr[i].w, qreg[mm][i].w, a3);
            }
            float s0 = (a0 + a1) + (a2 + a3);
            s0 += __shfl_xor(s0, 16);
            s0 += __shfl_xor(s0, 32);
            if (ds == 0) s_p[w * 4 + mm][s * 16 + tloc] = s0 * RSQRT_D;
        }
    }

    // ================= softmax =================
    asm volatile("s_waitcnt lgkmcnt(0)" ::: "memory");
    __builtin_amdgcn_s_barrier();
    {
        int m2 = tid >> 4, tl = tid & 15;
        float mx = -1e30f;
        for (int t = tl; t < nT; t += 16) mx = fmaxf(mx, s_p[m2][t]);
        #pragma unroll
        for (int o = 8; o; o >>= 1) mx = fmaxf(mx, __shfl_xor(mx, o));
        float sm = 0.f;
        for (int t = tl; t < nT; t += 16) {
            float p = __expf(s_p[m2][t] - mx);
            s_p[m2][t] = p;
            sm += p;
        }
        #pragma unroll
        for (int o = 8; o; o >>= 1) sm += __shfl_xor(sm, o);
        if (tl == 0) {
            float* msp = ms + ((size_t)(h * NCH + c) * 16 + m2) * 2;
            msp[0] = mx; msp[1] = sm;
        }
    }
    // PV's first (vmcnt+lgkmcnt+barrier) publishes the softmax writes

    // ================= V steps: PV =================
    float2 acc[4] = {{0.f,0.f},{0.f,0.f},{0.f,0.f},{0.f,0.f}};
    for (int j = 0; j < NST; ++j) {
        int s = NST + j;
        if (s == lastSlot) asm volatile("s_waitcnt vmcnt(0) lgkmcnt(0)" ::: "memory");
        else               asm volatile("s_waitcnt vmcnt(2) lgkmcnt(0)" ::: "memory");
        __builtin_amdgcn_s_barrier();
        float2 vr[16];
        const float* vbase = s_v[j & 1];
        #pragma unroll
        for (int r = 0; r < 16; ++r)
            vr[r] = *(const float2*)(vbase + (r >> 1) * 260 + (r & 1) * 128 + lane * 2);
        asm volatile("s_waitcnt lgkmcnt(0)" ::: "memory");
        __builtin_amdgcn_s_barrier();
        issue(s + 2);
        #pragma unroll
        for (int mm = 0; mm < 4; ++mm) {
            int m = w * 4 + mm;
            const float* prow = &s_p[m][j * 16];
            #pragma unroll
            for (int g4 = 0; g4 < 4; ++g4) {
                float4 p4 = *(const float4*)(prow + g4 * 4);
                acc[mm].x = fmaf(p4.x, vr[g4*4+0].x, acc[mm].x);
                acc[mm].y = fmaf(p4.x, vr[g4*4+0].y, acc[mm].y);
                acc[mm].x = fmaf(p4.y, vr[g4*4+1].x, acc[mm].x);
                acc[mm].y = fmaf(p4.y, vr[g4*4+1].y, acc[mm].y);
                acc[mm].x = fmaf(p4.z, vr[g4*4+2].x, acc[mm].x);
                acc[mm].y = fmaf(p4.z, vr[g4*4+2].y, acc[mm].y);
                acc[mm].x = fmaf(p4.w, vr[g4*4+3].x, acc[mm].x);
                acc[mm].y = fmaf(p4.w, vr[g4*4+3].y, acc[mm].y);
            }
        }
    }

    float* dp = part + (((size_t)(h * NCH + c) * 16) + w * 4) * DHEAD + 2 * lane;
    #pragma unroll
    for (int mm = 0; mm < 4; ++mm)
        *(float2*)(dp + (size_t)mm * DHEAD) = acc[mm];
}

// ---------------- combine chunk partials: block per (head, 16-d slice) -------
__global__ __launch_bounds__(256) void k_combine(const float* __restrict__ part,
                                                 const float* __restrict__ ms,
                                                 float* __restrict__ attnout) {
    __shared__ float s_scale[16][NCH + 3];
    int h = blockIdx.x >> 3, dblk = blockIdx.x & 7;
    int tid = threadIdx.x;
    {
        int cl = tid & 15, m = tid >> 4;
        float gmax = -1e30f;
        for (int c = cl; c < NCH; c += 16)
            gmax = fmaxf(gmax, ms[((size_t)(h * NCH + c) * 16 + m) * 2]);
        #pragma unroll
        for (int o = 8; o; o >>= 1) gmax = fmaxf(gmax, __shfl_xor(gmax, o));
        float denom = 0.f;
        for (int c = cl; c < NCH; c += 16) {
            const float* msp = ms + ((size_t)(h * NCH + c) * 16 + m) * 2;
            denom += msp[1] * __expf(msp[0] - gmax);
        }
        #pragma unroll
        for (int o = 8; o; o >>= 1) denom += __shfl_xor(denom, o);
        float inv = 1.f / denom;
        for (int c = cl; c < NCH; c += 16) {
            const float* msp = ms + ((size_t)(h * NCH + c) * 16 + m) * 2;
            s_scale[m][c] = __expf(msp[0] - gmax) * inv;
        }
    }
    __syncthreads();
    int m = tid >> 4, dd = tid & 15;
    int d = dblk * 16 + dd;
    const float* pp = part + ((size_t)h * NCH * 16 + m) * DHEAD + d;
    float acc = 0.f;
    #pragma unroll 4
    for (int c = 0; c < NCH; ++c)
        acc = fmaf(pp[(size_t)c * 16 * DHEAD], s_scale[m][c], acc);
    attnout[(size_t)m * NDIM + h * DHEAD + d] = acc;
}

// ---------------- launcher ----------------
extern "C" void kernel_launch(void* const* d_in, const int* in_sizes, int n_in,
                              void* d_out, int out_size, void* d_ws, size_t ws_size,
                              hipStream_t stream) {
    const float* X      = (const float*)d_in[0];
    const float* ln1_g  = (const float*)d_in[1];
    const float* ln1_b  = (const float*)d_in[2];
    const float* Wq     = (const float*)d_in[3];
    const float* Wk     = (const float*)d_in[4];
    const float* Wv     = (const float*)d_in[5];
    const float* Wo     = (const float*)d_in[6];
    const float* ln2_g  = (const float*)d_in[7];
    const float* ln2_b  = (const float*)d_in[8];
    const float* Wup    = (const float*)d_in[9];
    const float* Wdown  = (const float*)d_in[10];
    const float* cacheK = (const float*)d_in[11];
    const float* cacheV = (const float*)d_in[12];
    float* out = (float*)d_out;

    float* ws = (float*)d_ws;
    float* Xn1    = ws;                       // 32768
    float* qws    = Xn1 + 32768;              // 32768
    float* kws    = qws + 32768;              // 32768
    float* vws    = kws + 32768;              // 32768
    float* partb  = vws + 32768;              // 16*65*16*128 = 2129920
    float* msb    = partb + 2129920;          // 16*65*16*2   = 33280
    float* attn_o = msb + 33280;              // 32768
    float* X2     = attn_o + 32768;           // 32768
    float* Xn2    = X2 + 32768;               // 32768
    float* ffnh   = Xn2 + 32768;              // 131072

    k_ln<<<M_TOK, 256, 0, stream>>>(X, ln1_g, ln1_b, Xn1);
    k_qkv<<<1536, 256, 0, stream>>>(Xn1, Wq, Wk, Wv, qws, kws, vws);
    k_attn<<<NHEAD * NCH, 256, 0, stream>>>(cacheK, cacheV, qws, kws, vws, partb, msb);
    k_combine<<<NHEAD * 8, 256, 0, stream>>>(partb, msb, attn_o);
    k_resid<2048><<<512, 256, 0, stream>>>(attn_o, Wo, X, X2);
    k_ln<<<M_TOK, 256, 0, stream>>>(X2, ln2_g, ln2_b, Xn2);
    k_up<<<2048, 256, 0, stream>>>(Xn2, Wup, ffnh);
    k_resid<8192><<<512, 256, 0, stream>>>(ffnh, Wdown, X2, out);
}